// Round 13
// baseline (2483.134 us; speedup 1.0000x reference)
//
#include <hip/hip_runtime.h>

typedef _Float16 h8 __attribute__((ext_vector_type(8)));
typedef float f4 __attribute__((ext_vector_type(4)));

namespace {

constexpr int DM   = 768;
constexpr int NHEAD= 8;
constexpr int DQ   = 96;
constexpr int DFF  = 3072;
constexpr int NL   = 6;
constexpr int B_   = 64;
constexpr int T0   = 396, T1 = 198, T2 = 99;
constexpr int FIN  = 128;
constexpr int L_   = 100;
constexpr int MSEQ = B_ * L_;    // 6400
constexpr int M1   = B_ * T1;    // 12672
constexpr int M2   = B_ * T2;    // 6336
constexpr int NREL = 201;
constexpr int POSN = 256;        // padded 199 -> 256
constexpr int RELK = 128;        // padded K for pos GEMM (96 -> 128)

enum { EPI_F32 = 0, EPI_RELU_H, EPI_H, EPI_CONV_BN_H, EPI_CONV_RELU_H,
       EPI_CONV_ADD_RELU_H, EPI_ADD_F32 };

__device__ __forceinline__ void g2l16(const _Float16* g, _Float16* l)
{
    __builtin_amdgcn_global_load_lds(
        (const __attribute__((address_space(1))) unsigned int*)g,
        (__attribute__((address_space(3))) unsigned int*)l,
        16, 0, 0);
}

// ---------------------------------------------------------------------------
// Shared epilogue (NI = N-frags per wave). C/D map: col=lane&15, row=(lane>>4)*4+reg.
// ---------------------------------------------------------------------------
template<int EPI, bool OPAD, int MI, int NI>
__device__ __forceinline__ void epilogue(
    f4 (&acc)[MI][NI], int lane, int m0, int wm, int n0, int wn,
    int M, int N, int T_out, int bz,
    float* Cf, _Float16* Ch, const float* bias, const float* bns,
    const float* bnb, const _Float16* res, const float* resf, size_t c_z)
{
    const int frc = lane & 15;
    const int fq4 = (lane >> 4) * 4;
    float*    Cfo = Cf ? Cf + (size_t)bz * c_z : nullptr;
    _Float16* Cho = Ch ? Ch + (size_t)bz * c_z : nullptr;
    #pragma unroll
    for (int mi = 0; mi < MI; ++mi)
        #pragma unroll
        for (int ni = 0; ni < NI; ++ni)
            #pragma unroll
            for (int r = 0; r < 4; ++r) {
                int row = m0 + wm + mi * 16 + fq4 + r;
                int col = n0 + wn + ni * 16 + frc;
                if (row >= M) continue;
                float v = acc[mi][ni][r];
                size_t roff;
                if (OPAD) {
                    int ab = row / T_out, at = row - ab * T_out;
                    roff = ((size_t)ab * (T_out + 2) + at + 1) * N + col;
                } else {
                    roff = (size_t)row * N + col;
                }
                if (EPI == EPI_F32) {
                    if (bias) v += bias[col];
                    Cfo[roff] = v;
                } else if (EPI == EPI_ADD_F32) {
                    if (bias) v += bias[col];
                    v += resf[(size_t)row * N + col];
                    Cfo[roff] = v;
                } else if (EPI == EPI_RELU_H) {
                    if (bias) v += bias[col];
                    Cho[roff] = (_Float16)fmaxf(v, 0.0f);
                } else if (EPI == EPI_H) {
                    Cho[roff] = (_Float16)v;
                } else if (EPI == EPI_CONV_BN_H) {
                    v = bns[col] * (v + bias[col]) + bnb[col];
                    Cho[roff] = (_Float16)v;
                } else if (EPI == EPI_CONV_RELU_H) {
                    v = bns[col] * (v + bias[col]) + bnb[col];
                    Cho[roff] = (_Float16)fmaxf(v, 0.0f);
                } else { // EPI_CONV_ADD_RELU_H (f16 residual)
                    v = bns[col] * (v + bias[col]) + bnb[col]
                      + (float)res[(size_t)row * N + col];
                    Cho[roff] = (_Float16)fmaxf(v, 0.0f);
                }
            }
}

// ---------------------------------------------------------------------------
// CONV GEMM (R6/R11-validated gemm5): BK=64, single-buffer, 2-barrier, 32KB.
// ---------------------------------------------------------------------------
template<int EPI, bool OPAD, int MI>
__global__ __launch_bounds__(256)
void gemm5_k(const _Float16* __restrict__ A, const _Float16* __restrict__ B,
             float* __restrict__ Cf, _Float16* __restrict__ Ch,
             const float* __restrict__ bias, const float* __restrict__ bns,
             const float* __restrict__ bnb, const _Float16* __restrict__ res,
             int M, int N, int K, int lda,
             int T_out, int Tp_in, int stride_t, int KS, int in_off,
             int gx, int gxy)
{
    constexpr int TM = MI * 32;
    __shared__ _Float16 As[TM * 64];
    __shared__ _Float16 Bs[128 * 64];

    const unsigned nwg = gridDim.x, orig = blockIdx.x;
    const unsigned q = nwg >> 3, rr_ = nwg & 7;
    const unsigned xcd = orig & 7, idx = orig >> 3;
    const unsigned wgid = (xcd < rr_) ? xcd * (q + 1) + idx
                                      : rr_ * (q + 1) + (xcd - rr_) * q + idx;
    const int by  = (int)(wgid / (unsigned)gx);
    const int bx  = (int)(wgid - (unsigned)by * (unsigned)gx);
    (void)gxy;

    const int tid  = threadIdx.x;
    const int lane = tid & 63;
    const int wid  = tid >> 6;
    const int m0   = by * TM;
    const int n0   = bx * 128;
    const int wm   = (wid >> 1) * (MI * 16);
    const int wn   = (wid & 1) * 64;

    f4 acc[MI][4];
    #pragma unroll
    for (int i = 0; i < MI; ++i)
        #pragma unroll
        for (int j = 0; j < 4; ++j)
            #pragma unroll
            for (int p = 0; p < 4; ++p) acc[i][j][p] = 0.0f;

    const int colh = (((lane & 7) ^ ((lane >> 3) & 7)) << 3);
    size_t aoff[MI];
    #pragma unroll
    for (int i = 0; i < MI; ++i) {
        int m = min(m0 + wid * (MI * 8) + i * 8 + (lane >> 3), M - 1);
        int ab = m / T_out, at = m - ab * T_out;
        aoff[i] = ((size_t)ab * Tp_in + at * stride_t + in_off) * lda + colh;
    }
    size_t boff[4];
    #pragma unroll
    for (int i = 0; i < 4; ++i)
        boff[i] = (size_t)(n0 + wid * 32 + i * 8 + (lane >> 3)) * K + colh;
    const size_t bdk = (size_t)N * K;

    const int fr  = lane & 15;
    const int grp = lane >> 4;

    for (int dk = 0; dk < KS; ++dk) {
        const size_t adk = (size_t)dk * lda;
        const size_t bdo = (size_t)dk * bdk;

        for (int k0 = 0; k0 < K; k0 += 64) {
            #pragma unroll
            for (int i = 0; i < MI; ++i)
                g2l16(A + aoff[i] + adk + k0, &As[(wid * (MI * 8) + i * 8) * 64]);
            #pragma unroll
            for (int i = 0; i < 4; ++i)
                g2l16(B + boff[i] + bdo + k0, &Bs[(wid * 32 + i * 8) * 64]);
            __syncthreads();

            #pragma unroll
            for (int kh = 0; kh < 2; ++kh) {
                const int co = (((kh * 4 + grp) ^ (fr & 7)) << 3);
                h8 af[MI], bf[4];
                #pragma unroll
                for (int mi = 0; mi < MI; ++mi)
                    af[mi] = *(const h8*)&As[(wm + mi * 16 + fr) * 64 + co];
                #pragma unroll
                for (int ni = 0; ni < 4; ++ni)
                    bf[ni] = *(const h8*)&Bs[(wn + ni * 16 + fr) * 64 + co];
                #pragma unroll
                for (int mi = 0; mi < MI; ++mi)
                    #pragma unroll
                    for (int ni = 0; ni < 4; ++ni)
                        acc[mi][ni] = __builtin_amdgcn_mfma_f32_16x16x32_f16(
                            af[mi], bf[ni], acc[mi][ni], 0, 0, 0);
            }
            __syncthreads();
        }
    }

    epilogue<EPI, OPAD, MI, 4>(acc, lane, m0, wm, n0, wn, M, N, T_out, 0,
                               Cf, Ch, bias, bns, bnb, res, nullptr, 0);
}

// ---------------------------------------------------------------------------
// FC GEMM (R10/R11-validated gemm6): 128-wide N-tile, BK=64, ping-pong dbuf,
// ONE barrier per step. Used for wo/ff2/w_in/pos (small N or small K).
// ---------------------------------------------------------------------------
template<int EPI, int MI>
__global__ __launch_bounds__(256)
void gemm6_k(const _Float16* __restrict__ A, const _Float16* __restrict__ B,
             float* __restrict__ Cf, _Float16* __restrict__ Ch,
             const float* __restrict__ bias, const float* __restrict__ resf,
             int M, int N, int K, int lda,
             int gx, int gxy,
             size_t a_z, size_t b_z, size_t c_z)
{
    constexpr int TM = MI * 32;
    __shared__ _Float16 As[2][TM * 64];
    __shared__ _Float16 Bs[2][128 * 64];

    const unsigned nwg = gridDim.x, orig = blockIdx.x;
    const unsigned q = nwg >> 3, rr_ = nwg & 7;
    const unsigned xcd = orig & 7, idx = orig >> 3;
    const unsigned wgid = (xcd < rr_) ? xcd * (q + 1) + idx
                                      : rr_ * (q + 1) + (xcd - rr_) * q + idx;
    const int bz  = (int)(wgid / (unsigned)gxy);
    const int rem = (int)(wgid - (unsigned)bz * (unsigned)gxy);
    const int by  = rem / gx;
    const int bx  = rem - by * gx;

    A += (size_t)bz * a_z;
    B += (size_t)bz * b_z;

    const int tid  = threadIdx.x;
    const int lane = tid & 63;
    const int wid  = tid >> 6;
    const int m0   = by * TM;
    const int n0   = bx * 128;
    const int wm   = (wid >> 1) * (MI * 16);
    const int wn   = (wid & 1) * 64;

    f4 acc[MI][4];
    #pragma unroll
    for (int i = 0; i < MI; ++i)
        #pragma unroll
        for (int j = 0; j < 4; ++j)
            #pragma unroll
            for (int p = 0; p < 4; ++p) acc[i][j][p] = 0.0f;

    const int colh = (((lane & 7) ^ ((lane >> 3) & 7)) << 3);
    size_t aoff[MI];
    #pragma unroll
    for (int i = 0; i < MI; ++i) {
        int m = min(m0 + wid * (MI * 8) + i * 8 + (lane >> 3), M - 1);
        aoff[i] = (size_t)m * lda + colh;
    }
    size_t boff[4];
    #pragma unroll
    for (int i = 0; i < 4; ++i)
        boff[i] = (size_t)(n0 + wid * 32 + i * 8 + (lane >> 3)) * K + colh;

    const int fr  = lane & 15;
    const int grp = lane >> 4;
    const int NS  = K >> 6;

    auto stage = [&](int step, int buf) {
        const int k0 = step << 6;
        #pragma unroll
        for (int i = 0; i < MI; ++i)
            g2l16(A + aoff[i] + k0, &As[buf][(wid * (MI * 8) + i * 8) * 64]);
        #pragma unroll
        for (int i = 0; i < 4; ++i)
            g2l16(B + boff[i] + k0, &Bs[buf][(wid * 32 + i * 8) * 64]);
    };

    stage(0, 0);
    __syncthreads();

    for (int step = 0; step < NS; ++step) {
        const int cur = step & 1;
        const _Float16* As_ = As[cur];
        const _Float16* Bs_ = Bs[cur];

        const int co0 = ((grp ^ (fr & 7)) << 3);
        h8 af0[MI], bf0[4];
        #pragma unroll
        for (int mi = 0; mi < MI; ++mi)
            af0[mi] = *(const h8*)&As_[(wm + mi * 16 + fr) * 64 + co0];
        #pragma unroll
        for (int ni = 0; ni < 4; ++ni)
            bf0[ni] = *(const h8*)&Bs_[(wn + ni * 16 + fr) * 64 + co0];

        if (step + 1 < NS) stage(step + 1, cur ^ 1);

        #pragma unroll
        for (int mi = 0; mi < MI; ++mi)
            #pragma unroll
            for (int ni = 0; ni < 4; ++ni)
                acc[mi][ni] = __builtin_amdgcn_mfma_f32_16x16x32_f16(
                    af0[mi], bf0[ni], acc[mi][ni], 0, 0, 0);

        const int co1 = (((4 + grp) ^ (fr & 7)) << 3);
        h8 af1[MI], bf1[4];
        #pragma unroll
        for (int mi = 0; mi < MI; ++mi)
            af1[mi] = *(const h8*)&As_[(wm + mi * 16 + fr) * 64 + co1];
        #pragma unroll
        for (int ni = 0; ni < 4; ++ni)
            bf1[ni] = *(const h8*)&Bs_[(wn + ni * 16 + fr) * 64 + co1];
        #pragma unroll
        for (int mi = 0; mi < MI; ++mi)
            #pragma unroll
            for (int ni = 0; ni < 4; ++ni)
                acc[mi][ni] = __builtin_amdgcn_mfma_f32_16x16x32_f16(
                    af1[mi], bf1[ni], acc[mi][ni], 0, 0, 0);

        __syncthreads();
    }

    epilogue<EPI, false, MI, 4>(acc, lane, m0, wm, n0, wn, M, N, 0, bz,
                                Cf, Ch, bias, nullptr, nullptr, nullptr, resf, c_z);
}

// ---------------------------------------------------------------------------
// WIDE FC GEMM (NEW gemm8): 128x256 tile on gemm5's exact single-buffer /
// 2-barrier / BK=64 structure (parameter change only — same sync template).
// 4 waves, each 64x128 (acc[4][8]) -> 64 MFMA between barrier pairs (2x
// gemm6's 32), LDS 48KB -> 3 blocks/CU. For qkv (N=2304) and ff1 (N=3072).
// ---------------------------------------------------------------------------
template<int EPI>
__global__ __launch_bounds__(256)
void gemm8_k(const _Float16* __restrict__ A, const _Float16* __restrict__ B,
             float* __restrict__ Cf, _Float16* __restrict__ Ch,
             const float* __restrict__ bias,
             int M, int N, int K, int lda, int gx)
{
    __shared__ _Float16 As[128 * 64];
    __shared__ _Float16 Bs[256 * 64];

    const unsigned nwg = gridDim.x, orig = blockIdx.x;
    const unsigned q = nwg >> 3, rr_ = nwg & 7;
    const unsigned xcd = orig & 7, idx = orig >> 3;
    const unsigned wgid = (xcd < rr_) ? xcd * (q + 1) + idx
                                      : rr_ * (q + 1) + (xcd - rr_) * q + idx;
    const int by  = (int)(wgid / (unsigned)gx);
    const int bx  = (int)(wgid - (unsigned)by * (unsigned)gx);

    const int tid  = threadIdx.x;
    const int lane = tid & 63;
    const int wid  = tid >> 6;
    const int m0   = by * 128;
    const int n0   = bx * 256;
    const int wm   = (wid >> 1) * 64;
    const int wn   = (wid & 1) * 128;

    f4 acc[4][8];
    #pragma unroll
    for (int i = 0; i < 4; ++i)
        #pragma unroll
        for (int j = 0; j < 8; ++j)
            #pragma unroll
            for (int p = 0; p < 4; ++p) acc[i][j][p] = 0.0f;

    const int colh = (((lane & 7) ^ ((lane >> 3) & 7)) << 3);
    size_t aoff[4];
    #pragma unroll
    for (int i = 0; i < 4; ++i) {
        int m = min(m0 + wid * 32 + i * 8 + (lane >> 3), M - 1);
        aoff[i] = (size_t)m * lda + colh;
    }
    size_t boff[8];
    #pragma unroll
    for (int i = 0; i < 8; ++i)
        boff[i] = (size_t)(n0 + wid * 64 + i * 8 + (lane >> 3)) * K + colh;

    const int fr  = lane & 15;
    const int grp = lane >> 4;

    for (int k0 = 0; k0 < K; k0 += 64) {
        #pragma unroll
        for (int i = 0; i < 4; ++i)
            g2l16(A + aoff[i] + k0, &As[(wid * 32 + i * 8) * 64]);
        #pragma unroll
        for (int i = 0; i < 8; ++i)
            g2l16(B + boff[i] + k0, &Bs[(wid * 64 + i * 8) * 64]);
        __syncthreads();

        #pragma unroll
        for (int kh = 0; kh < 2; ++kh) {
            const int co = (((kh * 4 + grp) ^ (fr & 7)) << 3);
            h8 af[4], bf[8];
            #pragma unroll
            for (int mi = 0; mi < 4; ++mi)
                af[mi] = *(const h8*)&As[(wm + mi * 16 + fr) * 64 + co];
            #pragma unroll
            for (int ni = 0; ni < 8; ++ni)
                bf[ni] = *(const h8*)&Bs[(wn + ni * 16 + fr) * 64 + co];
            #pragma unroll
            for (int mi = 0; mi < 4; ++mi)
                #pragma unroll
                for (int ni = 0; ni < 8; ++ni)
                    acc[mi][ni] = __builtin_amdgcn_mfma_f32_16x16x32_f16(
                        af[mi], bf[ni], acc[mi][ni], 0, 0, 0);
        }
        __syncthreads();
    }

    epilogue<EPI, false, 4, 8>(acc, lane, m0, wm, n0, wn, M, N, 0, 0,
                               Cf, Ch, bias, nullptr, nullptr, nullptr, nullptr, 0);
}

// ------------------------- small helper kernels ----------------------------

__global__ void f2h8_k(const float* __restrict__ in, _Float16* __restrict__ out,
                       long n8)
{
    long i = (long)blockIdx.x * blockDim.x + threadIdx.x;
    if (i >= n8) return;
    f4 a = ((const f4*)in)[2 * i];
    f4 b = ((const f4*)in)[2 * i + 1];
    h8 o;
    #pragma unroll
    for (int j = 0; j < 4; ++j) { o[j] = (_Float16)a[j]; o[4 + j] = (_Float16)b[j]; }
    ((h8*)out)[i] = o;
}

__global__ void f2h_pad_k(const float* __restrict__ in, _Float16* __restrict__ out)
{
    long i = (long)blockIdx.x * blockDim.x + threadIdx.x;
    if (i >= (long)B_ * 398 * FIN) return;
    int  c = (int)(i % FIN);
    long r = i / FIN;
    int  t = (int)(r % 398);
    int  b = (int)(r / 398);
    float v = (t == 0 || t == 397) ? 0.0f
            : in[((long)b * T0 + (t - 1)) * FIN + c];
    out[i] = (_Float16)v;
}

__global__ void zero_pad_k(_Float16* __restrict__ buf, int Tp, int C)
{
    long i = (long)blockIdx.x * blockDim.x + threadIdx.x;
    if (i >= (long)B_ * 2 * C) return;
    int  c = (int)(i % C);
    long r = i / C;
    int  hi = (int)(r % 2);
    int  b  = (int)(r / 2);
    buf[((size_t)b * Tp + (hi ? Tp - 1 : 0)) * C + c] = (_Float16)0.0f;
}

__global__ void pack_qkv_k(const float* __restrict__ wq, const float* __restrict__ wk,
                           const float* __restrict__ wv, _Float16* __restrict__ out)
{
    long i = (long)blockIdx.x * blockDim.x + threadIdx.x;
    if (i >= (long)NL * 2304 * DM) return;
    int  f = (int)(i % DM);
    long r = i / DM;
    int  n = (int)(r % 2304);
    int  l = (int)(r / 2304);
    int  s = n / DM, hn = n % DM, h = hn / DQ, a = hn % DQ;
    const float* src = (s == 0) ? wq : ((s == 1) ? wk : wv);
    out[i] = (_Float16)src[(((long)l * NHEAD + h) * DM + f) * DQ + a];
}

__global__ void pack_wo_k(const float* __restrict__ wo, _Float16* __restrict__ out)
{
    long i = (long)blockIdx.x * blockDim.x + threadIdx.x;
    if (i >= (long)NL * DM * DM) return;
    int  ha = (int)(i % DM);
    long r  = i / DM;
    int  f  = (int)(r % DM);
    int  l  = (int)(r / DM);
    int  h = ha / DQ, a = ha % DQ;
    out[i] = (_Float16)wo[(((long)l * NHEAD + h) * DQ + a) * DM + f];
}

__global__ void pack_conv_k(const float* __restrict__ w, _Float16* __restrict__ out,
                            int Cout, int Cin, int KS)
{
    long i = (long)blockIdx.x * blockDim.x + threadIdx.x;
    if (i >= (long)Cout * Cin * KS) return;
    int  ci = (int)(i % Cin);
    long r  = i / Cin;
    int  co = (int)(r % Cout);
    int  dk = (int)(r / Cout);
    out[i] = (_Float16)w[((long)co * Cin + ci) * KS + dk];
}

__global__ void pack_rel_k(const float* __restrict__ rel, _Float16* __restrict__ out)
{
    long i = (long)blockIdx.x * blockDim.x + threadIdx.x;
    if (i >= (long)NL * NHEAD * POSN * RELK) return;
    int  k = (int)(i & (RELK - 1));
    long r = i >> 7;
    int  n = (int)(r & (POSN - 1));
    long r2 = r >> 8;
    int  h = (int)(r2 & (NHEAD - 1));
    int  l = (int)(r2 >> 3);
    float v = 0.0f;
    if (n < NREL && k < DQ)
        v = rel[(((long)l * NHEAD + h) * NREL + n) * DQ + k] * 0.10206207261596575f;
    out[i] = (_Float16)v;
}

__global__ void concat_k(const float* __restrict__ xlin, const float* __restrict__ cls,
                         float* __restrict__ xf, _Float16* __restrict__ xh)
{
    long i = (long)blockIdx.x * blockDim.x + threadIdx.x;
    if (i >= (long)MSEQ * DM) return;
    int  c = (int)(i % DM);
    long m = i / DM;
    int  b = (int)(m / L_), t = (int)(m % L_);
    float v = (t == 0) ? cls[c] : xlin[((long)b * (L_ - 1) + (t - 1)) * DM + c];
    xf[i] = v;
    xh[i] = (_Float16)v;
}

// LayerNorm over a pre-summed input s (residual already fused into GEMM epilogue)
__global__ __launch_bounds__(256)
void ln_k(const float* __restrict__ sIn,
          const float* __restrict__ g, const float* __restrict__ bb,
          float* __restrict__ xo, _Float16* __restrict__ xh)
{
    long row = blockIdx.x;
    const float* sr = sIn + row * DM;
    float v[3];
    float s = 0.0f;
    #pragma unroll
    for (int k = 0; k < 3; ++k) {
        int c = threadIdx.x + 256 * k;
        v[k] = sr[c];
        s += v[k];
    }
    __shared__ float red[8];
    #pragma unroll
    for (int o = 32; o; o >>= 1) s += __shfl_xor(s, o, 64);
    int w = threadIdx.x >> 6, lane = threadIdx.x & 63;
    if (lane == 0) red[w] = s;
    __syncthreads();
    s = red[0] + red[1] + red[2] + red[3];
    float mean = s * (1.0f / DM);
    float vs = 0.0f;
    #pragma unroll
    for (int k = 0; k < 3; ++k) { float t = v[k] - mean; vs += t * t; }
    #pragma unroll
    for (int o = 32; o; o >>= 1) vs += __shfl_xor(vs, o, 64);
    if (lane == 0) red[4 + w] = vs;
    __syncthreads();
    vs = red[4] + red[5] + red[6] + red[7];
    float rstd = rsqrtf(vs * (1.0f / DM) + 1e-5f);
    #pragma unroll
    for (int k = 0; k < 3; ++k) {
        int c = threadIdx.x + 256 * k;
        float y = (v[k] - mean) * rstd * g[c] + bb[c];
        xo[row * DM + c] = y;
        xh[row * DM + c] = (_Float16)y;
    }
}

// MFMA fused attention (unchanged — validated rounds 2-12).
constexpr int LP = 128;
constexpr int KP = 104;
constexpr int PP = 136;

__global__ __launch_bounds__(256)
void attn_k(const _Float16* __restrict__ qkv, const _Float16* __restrict__ pos,
            _Float16* __restrict__ o)
{
    __shared__ __align__(16) char smem[60928];
    _Float16* Ks = (_Float16*)smem;
    _Float16* Ps = (_Float16*)smem;
    _Float16* Vt = (_Float16*)(smem + 34816);

    const int h = blockIdx.x, b = blockIdx.y;
    const int tid = threadIdx.x, lane = tid & 63, w = tid >> 6;
    const _Float16* base = qkv + (size_t)b * L_ * 2304 + h * DQ;
    const float qscale = 0.10206207261596575f;

    {
        int row = tid >> 1;
        int c0  = (tid & 1) * 48;
        const bool real = row < L_;
        const _Float16* krow = base + 768 + (size_t)row * 2304;
        #pragma unroll
        for (int q = 0; q < 6; ++q) {
            int c = c0 + q * 8;
            h8 kv;
            #pragma unroll
            for (int e = 0; e < 8; ++e) kv[e] = (_Float16)0.0f;
            if (real) kv = *(const h8*)(krow + c);
            *(h8*)&Ks[row * KP + c] = kv;
        }
        for (int idx = tid; idx < DQ * LP; idx += 256) {
            int a = idx % DQ, j = idx / DQ;
            _Float16 v = (_Float16)0.0f;
            if (j < L_) v = base[1536 + (size_t)j * 2304 + a];
            Vt[a * PP + j] = v;
        }
    }
    __syncthreads();

    const int fr = lane & 15;
    const int fk = (lane >> 4) * 8;
    const int rbase = w * 32 + ((lane >> 4) << 2);

    f4 acc[2][8];
    #pragma unroll
    for (int mi = 0; mi < 2; ++mi)
        #pragma unroll
        for (int ni = 0; ni < 8; ++ni)
            #pragma unroll
            for (int q = 0; q < 4; ++q) acc[mi][ni][q] = 0.0f;

    #pragma unroll
    for (int k0 = 0; k0 < DQ; k0 += 32) {
        h8 a0 = *(const h8*)(base + (size_t)(w * 32 + fr) * 2304 + k0 + fk);
        h8 a1 = *(const h8*)(base + (size_t)(w * 32 + 16 + fr) * 2304 + k0 + fk);
        #pragma unroll
        for (int ni = 0; ni < 8; ++ni) {
            h8 bv = *(const h8*)&Ks[(ni * 16 + fr) * KP + k0 + fk];
            acc[0][ni] = __builtin_amdgcn_mfma_f32_16x16x32_f16(a0, bv, acc[0][ni], 0, 0, 0);
            acc[1][ni] = __builtin_amdgcn_mfma_f32_16x16x32_f16(a1, bv, acc[1][ni], 0, 0, 0);
        }
    }

    const _Float16* posb = pos + ((size_t)h * MSEQ + (size_t)b * L_) * POSN;
    #pragma unroll
    for (int mi = 0; mi < 2; ++mi)
        #pragma unroll
        for (int r = 0; r < 4; ++r) {
            int i = rbase + mi * 16 + r;
            float s[8];
            #pragma unroll
            for (int ni = 0; ni < 8; ++ni) {
                int j = ni * 16 + fr;
                float v = -3.0e38f;
                if (i < L_ && j < L_)
                    v = acc[mi][ni][r] * qscale
                      + (float)posb[(size_t)i * POSN + (j - i + (L_ - 1))];
                s[ni] = v;
            }
            float m = s[0];
            #pragma unroll
            for (int ni = 1; ni < 8; ++ni) m = fmaxf(m, s[ni]);
            #pragma unroll
            for (int msk = 1; msk < 16; msk <<= 1) m = fmaxf(m, __shfl_xor(m, msk, 64));
            float sum = 0.0f;
            #pragma unroll
            for (int ni = 0; ni < 8; ++ni) { s[ni] = __expf(s[ni] - m); sum += s[ni]; }
            #pragma unroll
            for (int msk = 1; msk < 16; msk <<= 1) sum += __shfl_xor(sum, msk, 64);
            float inv = 1.0f / sum;
            #pragma unroll
            for (int ni = 0; ni < 8; ++ni) acc[mi][ni][r] = s[ni] * inv;
        }

    __syncthreads();

    #pragma unroll
    for (int mi = 0; mi < 2; ++mi)
        #pragma unroll
        for (int r = 0; r < 4; ++r) {
            int i = rbase + mi * 16 + r;
            #pragma unroll
            for (int ni = 0; ni < 8; ++ni)
                Ps[i * PP + ni * 16 + fr] = (_Float16)acc[mi][ni][r];
        }
    __syncthreads();

    f4 acc2[2][6];
    #pragma unroll
    for (int mi = 0; mi < 2; ++mi)
        #pragma unroll
        for (int ni = 0; ni < 6; ++ni)
            #pragma unroll
            for (int q = 0; q < 4; ++q) acc2[mi][ni][q] = 0.0f;

    #pragma unroll
    for (int k0 = 0; k0 < LP; k0 += 32) {
        h8 a0 = *(const h8*)&Ps[(w * 32 + fr) * PP + k0 + fk];
        h8 a1 = *(const h8*)&Ps[(w * 32 + 16 + fr) * PP + k0 + fk];
        #pragma unroll
        for (int ni = 0; ni < 6; ++ni) {
            h8 bv = *(const h8*)&Vt[(ni * 16 + fr) * PP + k0 + fk];
            acc2[0][ni] = __builtin_amdgcn_mfma_f32_16x16x32_f16(a0, bv, acc2[0][ni], 0, 0, 0);
            acc2[1][ni] = __builtin_amdgcn_mfma_f32_16x16x32_f16(a1, bv, acc2[1][ni], 0, 0, 0);
        }
    }

    _Float16* ob = o + (size_t)b * L_ * DM + h * DQ;
    #pragma unroll
    for (int mi = 0; mi < 2; ++mi)
        #pragma unroll
        for (int r = 0; r < 4; ++r) {
            int i = rbase + mi * 16 + r;
            if (i < L_) {
                #pragma unroll
                for (int ni = 0; ni < 6; ++ni)
                    ob[(size_t)i * DM + ni * 16 + fr] = (_Float16)acc2[mi][ni][r];
            }
        }
}

__global__ __launch_bounds__(256)
void out_k(const float* __restrict__ xseq, const float* __restrict__ w,
           const float* __restrict__ bias, float* __restrict__ out)
{
    __shared__ float xs[DM];
    int b = blockIdx.x;
    for (int c = threadIdx.x; c < DM; c += 256) xs[c] = xseq[(size_t)b * L_ * DM + c];
    __syncthreads();
    int n = threadIdx.x;
    const f4* wr = (const f4*)(w + (size_t)n * DM);
    float acc = 0.0f;
    #pragma unroll 4
    for (int k4 = 0; k4 < DM / 4; ++k4) {
        f4 wv = wr[k4];
        f4 xv = *(const f4*)&xs[k4 * 4];
        acc += wv[0]*xv[0] + wv[1]*xv[1] + wv[2]*xv[2] + wv[3]*xv[3];
    }
    out[(size_t)b * 256 + n] = acc + bias[n];
}

} // anonymous namespace

// ---------------------------------------------------------------------------
extern "C" void kernel_launch(void* const* d_in, const int* in_sizes, int n_in,
                              void* d_out, int out_size, void* d_ws, size_t ws_size,
                              hipStream_t stream)
{
    (void)in_sizes; (void)n_in; (void)out_size; (void)ws_size;

    const float* x_raw   = (const float*)d_in[0];
    const float* rb1_c1w = (const float*)d_in[1];
    const float* rb1_c1b = (const float*)d_in[2];
    const float* rb1_s1  = (const float*)d_in[3];
    const float* rb1_b1  = (const float*)d_in[4];
    const float* rb1_c2w = (const float*)d_in[5];
    const float* rb1_c2b = (const float*)d_in[6];
    const float* rb1_s2  = (const float*)d_in[7];
    const float* rb1_b2  = (const float*)d_in[8];
    const float* rb1_crw = (const float*)d_in[9];
    const float* rb1_crb = (const float*)d_in[10];
    const float* rb1_sr  = (const float*)d_in[11];
    const float* rb1_br  = (const float*)d_in[12];
    const float* rb2_c1w = (const float*)d_in[13];
    const float* rb2_c1b = (const float*)d_in[14];
    const float* rb2_s1  = (const float*)d_in[15];
    const float* rb2_b1  = (const float*)d_in[16];
    const float* rb2_c2w = (const float*)d_in[17];
    const float* rb2_c2b = (const float*)d_in[18];
    const float* rb2_s2  = (const float*)d_in[19];
    const float* rb2_b2  = (const float*)d_in[20];
    const float* rb2_crw = (const float*)d_in[21];
    const float* rb2_crb = (const float*)d_in[22];
    const float* rb2_sr  = (const float*)d_in[23];
    const float* rb2_br  = (const float*)d_in[24];
    const float* w_in_w  = (const float*)d_in[25];
    const float* w_in_b  = (const float*)d_in[26];
    const float* cls     = (const float*)d_in[27];
    const float* wq      = (const float*)d_in[28];
    const float* wk      = (const float*)d_in[29];
    const float* wv      = (const float*)d_in[30];
    const float* wo      = (const float*)d_in[31];
    const float* rel     = (const float*)d_in[32];
    const float* ln1g    = (const float*)d_in[33];
    const float* ln1b    = (const float*)d_in[34];
    const float* ln2g    = (const float*)d_in[35];
    const float* ln2b    = (const float*)d_in[36];
    const float* ff1w    = (const float*)d_in[37];
    const float* ff1b    = (const float*)d_in[38];
    const float* ff2w    = (const float*)d_in[39];
    const float* ff2b    = (const float*)d_in[40];
    const float* w_out_w = (const float*)d_in[41];
    const float* w_out_b = (const float*)d_in[42];

    char* base = (char*)d_ws;
    size_t off = 0;
    auto carve = [&](size_t bytes) -> char* {
        char* p = base + off;
        off = (off + bytes + 255) & ~(size_t)255;
        return p;
    };
    _Float16* w_in_h = (_Float16*)carve((size_t)589824 * 2);
    _Float16* qkvw   = (_Float16*)carve((size_t)10616832 * 2);
    _Float16* wow    = (_Float16*)carve((size_t)3538944 * 2);
    _Float16* ff1h   = (_Float16*)carve((size_t)14155776 * 2);
    _Float16* ff2h   = (_Float16*)carve((size_t)14155776 * 2);
    _Float16* relh   = (_Float16*)carve((size_t)NL * NHEAD * POSN * RELK * 2);
    _Float16* cw11   = (_Float16*)carve((size_t)294912 * 2);
    _Float16* cw12   = (_Float16*)carve((size_t)1769472 * 2);
    _Float16* cw1r   = (_Float16*)carve((size_t)98304 * 2);
    _Float16* cw21   = (_Float16*)carve((size_t)1769472 * 2);
    _Float16* cw22   = (_Float16*)carve((size_t)1769472 * 2);
    _Float16* cw2r   = (_Float16*)carve((size_t)589824 * 2);
    _Float16* xrawp  = (_Float16*)carve((size_t)B_ * 398 * FIN * 2);
    float*    xseq_f = (float*)carve((size_t)4915200 * 4);
    _Float16* xseq_h = (_Float16*)carve((size_t)4915200 * 2);
    _Float16* qkvb   = (_Float16*)carve((size_t)14745600 * 2);
    _Float16* ohb    = (_Float16*)carve((size_t)4915200 * 2);
    float*    af     = (float*)carve((size_t)4915200 * 4);
    char*     hhreg  = carve((size_t)19660800 * 2);
    float*    yf     = (float*)carve((size_t)4915200 * 4);
    // phase-overlapped aliases (strictly sequential producer->consumer):
    _Float16* h1_rb1 = qkvb;                 // [64][200][768] padded
    _Float16* r_rb1h = (_Float16*)hhreg;     // [12672][768] f16 residual
    _Float16* out1   = (_Float16*)af;        // [64][200][768] padded
    _Float16* h1_rb2 = (_Float16*)xseq_f;    // [64][101][768] padded
    _Float16* r_rb2h = (_Float16*)yf;        // [6336][768] f16 residual
    _Float16* out2   = ohb;                  // [6336][768] plain
    float*    xlin   = (float*)hhreg;
    _Float16* posh   = (_Float16*)hhreg;
    _Float16* ffh    = (_Float16*)hhreg;

    dim3 blk(256, 1, 1);
    auto grd = [](long n) { return dim3((unsigned)((n + 255) / 256), 1, 1); };
    #define NWG(M, N, TM, GZ) dim3((unsigned)(((N) / 128) * (((M) + (TM) - 1) / (TM)) * (GZ)), 1, 1)
    #define GXY(M, N, TM) ((N) / 128), (((N) / 128) * (((M) + (TM) - 1) / (TM)))
    #define NWG8(M, N) dim3((unsigned)(((N) / 256) * ((M) / 128)), 1, 1)

    // ---- weight conversion / packing ----
    f2h_pad_k<<<grd((long)B_ * 398 * FIN), blk, 0, stream>>>(x_raw, xrawp);
    zero_pad_k<<<grd((long)B_ * 2 * DM), blk, 0, stream>>>(h1_rb1, 200, DM);
    zero_pad_k<<<grd((long)B_ * 2 * DM), blk, 0, stream>>>(out1, 200, DM);
    zero_pad_k<<<grd((long)B_ * 2 * DM), blk, 0, stream>>>(h1_rb2, 101, DM);
    f2h8_k<<<grd(589824 / 8), blk, 0, stream>>>(w_in_w, w_in_h, 589824 / 8);
    f2h8_k<<<grd(14155776 / 8), blk, 0, stream>>>(ff1w, ff1h, 14155776 / 8);
    f2h8_k<<<grd(14155776 / 8), blk, 0, stream>>>(ff2w, ff2h, 14155776 / 8);
    pack_rel_k<<<grd((long)NL * NHEAD * POSN * RELK), blk, 0, stream>>>(rel, relh);
    pack_qkv_k<<<grd((long)NL * 2304 * DM), blk, 0, stream>>>(wq, wk, wv, qkvw);
    pack_wo_k<<<grd((long)NL * DM * DM), blk, 0, stream>>>(wo, wow);
    pack_conv_k<<<grd(294912), blk, 0, stream>>>(rb1_c1w, cw11, DM, FIN, 3);
    pack_conv_k<<<grd(1769472), blk, 0, stream>>>(rb1_c2w, cw12, DM, DM, 3);
    pack_conv_k<<<grd(98304), blk, 0, stream>>>(rb1_crw, cw1r, DM, FIN, 1);
    pack_conv_k<<<grd(1769472), blk, 0, stream>>>(rb2_c1w, cw21, DM, DM, 3);
    pack_conv_k<<<grd(1769472), blk, 0, stream>>>(rb2_c2w, cw22, DM, DM, 3);
    pack_conv_k<<<grd(589824), blk, 0, stream>>>(rb2_crw, cw2r, DM, DM, 1);

    // ---- resblock 1 (T 396 -> 198); MI=4 ----
    gemm5_k<EPI_CONV_BN_H, false, 4><<<NWG(M1, DM, 128, 1), blk, 0, stream>>>(
        xrawp, cw1r, nullptr, r_rb1h, rb1_crb, rb1_sr, rb1_br, nullptr,
        M1, DM, FIN, FIN, T1, 398, 2, 1, 1, GXY(M1, DM, 128));
    gemm5_k<EPI_CONV_RELU_H, true, 4><<<NWG(M1, DM, 128, 1), blk, 0, stream>>>(
        xrawp, cw11, nullptr, h1_rb1, rb1_c1b, rb1_s1, rb1_b1, nullptr,
        M1, DM, FIN, FIN, T1, 398, 2, 3, 0, GXY(M1, DM, 128));
    gemm5_k<EPI_CONV_ADD_RELU_H, true, 4><<<NWG(M1, DM, 128, 1), blk, 0, stream>>>(
        h1_rb1, cw12, nullptr, out1, rb1_c2b, rb1_s2, rb1_b2, r_rb1h,
        M1, DM, DM, DM, T1, 200, 1, 3, 0, GXY(M1, DM, 128));

    // ---- resblock 2 (T 198 -> 99); MI=2 ----
    gemm5_k<EPI_CONV_BN_H, false, 2><<<NWG(M2, DM, 64, 1), blk, 0, stream>>>(
        out1, cw2r, nullptr, r_rb2h, rb2_crb, rb2_sr, rb2_br, nullptr,
        M2, DM, DM, DM, T2, 200, 2, 1, 1, GXY(M2, DM, 64));
    gemm5_k<EPI_CONV_RELU_H, true, 2><<<NWG(M2, DM, 64, 1), blk, 0, stream>>>(
        out1, cw21, nullptr, h1_rb2, rb2_c1b, rb2_s1, rb2_b1, nullptr,
        M2, DM, DM, DM, T2, 200, 2, 3, 0, GXY(M2, DM, 64));
    gemm5_k<EPI_CONV_ADD_RELU_H, false, 2><<<NWG(M2, DM, 64, 1), blk, 0, stream>>>(
        h1_rb2, cw22, nullptr, out2, rb2_c2b, rb2_s2, rb2_b2, r_rb2h,
        M2, DM, DM, DM, T2, 101, 1, 3, 0, GXY(M2, DM, 64));

    // ---- input projection + cls concat ----
    gemm6_k<EPI_F32, 2><<<NWG(M2, DM, 64, 1), blk, 0, stream>>>(
        out2, w_in_h, xlin, nullptr, w_in_b, nullptr,
        M2, DM, DM, DM, GXY(M2, DM, 64), 0, 0, 0);
    concat_k<<<grd((long)MSEQ * DM), blk, 0, stream>>>(xlin, cls, xseq_f, xseq_h);

    // ---- transformer layers ----
    for (int l = 0; l < NL; ++l) {
        gemm8_k<EPI_H><<<NWG8(MSEQ, 2304), blk, 0, stream>>>(
            xseq_h, qkvw + (size_t)l * 2304 * DM, nullptr, qkvb, nullptr,
            MSEQ, 2304, DM, DM, 2304 / 256);
        gemm6_k<EPI_H, 4><<<NWG(MSEQ, POSN, 128, NHEAD), blk, 0, stream>>>(
            qkvb, relh + (size_t)l * NHEAD * POSN * RELK, nullptr, posh, nullptr, nullptr,
            MSEQ, POSN, RELK, 2304, GXY(MSEQ, POSN, 128),
            (size_t)DQ, (size_t)POSN * RELK, (size_t)MSEQ * POSN);
        attn_k<<<dim3(NHEAD, B_, 1), blk, 0, stream>>>(qkvb, posh, ohb);
        // wo: delta + residual fused (af = xseq_f + attn_out @ wo^T)
        gemm6_k<EPI_ADD_F32, 2><<<NWG(MSEQ, DM, 64, 1), blk, 0, stream>>>(
            ohb, wow + (size_t)l * DM * DM, af, nullptr, nullptr, xseq_f,
            MSEQ, DM, DM, DM, GXY(MSEQ, DM, 64), 0, 0, 0);
        ln_k<<<dim3(MSEQ), blk, 0, stream>>>(af, ln1g + l * DM, ln1b + l * DM,
                                             xseq_f, xseq_h);
        gemm8_k<EPI_RELU_H><<<NWG8(MSEQ, DFF), blk, 0, stream>>>(
            xseq_h, ff1h + (size_t)l * DFF * DM, nullptr, ffh, ff1b + l * DFF,
            MSEQ, DFF, DM, DM, DFF / 256);
        // ff2: delta + residual fused (yf = xseq_f + relu(ff1) @ ff2^T + b)
        gemm6_k<EPI_ADD_F32, 2><<<NWG(MSEQ, DM, 64, 1), blk, 0, stream>>>(
            ffh, ff2h + (size_t)l * DM * DFF, yf, nullptr, ff2b + l * DM, xseq_f,
            MSEQ, DM, DFF, DFF, GXY(MSEQ, DM, 64), 0, 0, 0);
        ln_k<<<dim3(MSEQ), blk, 0, stream>>>(yf, ln2g + l * DM, ln2b + l * DM,
                                             xseq_f, xseq_h);
    }

    out_k<<<dim3(B_), blk, 0, stream>>>(xseq_f, w_out_w, w_out_b, (float*)d_out);
    #undef NWG
    #undef GXY
    #undef NWG8
}

// Round 14
// 2053.504 us; speedup vs baseline: 1.2092x; 1.2092x over previous
//
#include <hip/hip_runtime.h>

typedef _Float16 h8 __attribute__((ext_vector_type(8)));
typedef float f4 __attribute__((ext_vector_type(4)));

namespace {

constexpr int DM   = 768;
constexpr int NHEAD= 8;
constexpr int DQ   = 96;
constexpr int DFF  = 3072;
constexpr int NL   = 6;
constexpr int B_   = 64;
constexpr int T0   = 396, T1 = 198, T2 = 99;
constexpr int FIN  = 128;
constexpr int L_   = 100;
constexpr int MSEQ = B_ * L_;    // 6400
constexpr int M1   = B_ * T1;    // 12672
constexpr int M2   = B_ * T2;    // 6336
constexpr int NREL = 201;
constexpr int POSN = 256;        // padded 199 -> 256
constexpr int RELK = 128;        // padded K for pos GEMM (96 -> 128)

enum { EPI_F32 = 0, EPI_RELU_H, EPI_H, EPI_CONV_BN_H, EPI_CONV_RELU_H,
       EPI_CONV_ADD_RELU_H, EPI_ADD_F32 };

__device__ __forceinline__ void g2l16(const _Float16* g, _Float16* l)
{
    __builtin_amdgcn_global_load_lds(
        (const __attribute__((address_space(1))) unsigned int*)g,
        (__attribute__((address_space(3))) unsigned int*)l,
        16, 0, 0);
}

// ---------------------------------------------------------------------------
// Shared epilogue. C/D map: col=lane&15, row=(lane>>4)*4+reg.
// ---------------------------------------------------------------------------
template<int EPI, bool OPAD, int MI>
__device__ __forceinline__ void epilogue(
    f4 (&acc)[MI][4], int lane, int m0, int wm, int n0, int wn,
    int M, int N, int T_out, int bz,
    float* Cf, _Float16* Ch, const float* bias, const float* bns,
    const float* bnb, const _Float16* res, const float* resf, size_t c_z)
{
    const int frc = lane & 15;
    const int fq4 = (lane >> 4) * 4;
    float*    Cfo = Cf ? Cf + (size_t)bz * c_z : nullptr;
    _Float16* Cho = Ch ? Ch + (size_t)bz * c_z : nullptr;
    #pragma unroll
    for (int mi = 0; mi < MI; ++mi)
        #pragma unroll
        for (int ni = 0; ni < 4; ++ni)
            #pragma unroll
            for (int r = 0; r < 4; ++r) {
                int row = m0 + wm + mi * 16 + fq4 + r;
                int col = n0 + wn + ni * 16 + frc;
                if (row >= M) continue;
                float v = acc[mi][ni][r];
                size_t roff;
                if (OPAD) {
                    int ab = row / T_out, at = row - ab * T_out;
                    roff = ((size_t)ab * (T_out + 2) + at + 1) * N + col;
                } else {
                    roff = (size_t)row * N + col;
                }
                if (EPI == EPI_F32) {
                    if (bias) v += bias[col];
                    Cfo[roff] = v;
                } else if (EPI == EPI_ADD_F32) {
                    if (bias) v += bias[col];
                    v += resf[(size_t)row * N + col];
                    Cfo[roff] = v;
                } else if (EPI == EPI_RELU_H) {
                    if (bias) v += bias[col];
                    Cho[roff] = (_Float16)fmaxf(v, 0.0f);
                } else if (EPI == EPI_H) {
                    Cho[roff] = (_Float16)v;
                } else if (EPI == EPI_CONV_BN_H) {
                    v = bns[col] * (v + bias[col]) + bnb[col];
                    Cho[roff] = (_Float16)v;
                } else if (EPI == EPI_CONV_RELU_H) {
                    v = bns[col] * (v + bias[col]) + bnb[col];
                    Cho[roff] = (_Float16)fmaxf(v, 0.0f);
                } else { // EPI_CONV_ADD_RELU_H (f16 residual)
                    v = bns[col] * (v + bias[col]) + bnb[col]
                      + (float)res[(size_t)row * N + col];
                    Cho[roff] = (_Float16)fmaxf(v, 0.0f);
                }
            }
}

// ---------------------------------------------------------------------------
// CONV GEMM (R6/R11-validated gemm5): BK=64, single-buffer, 2-barrier, 32KB.
// ---------------------------------------------------------------------------
template<int EPI, bool OPAD, int MI>
__global__ __launch_bounds__(256)
void gemm5_k(const _Float16* __restrict__ A, const _Float16* __restrict__ B,
             float* __restrict__ Cf, _Float16* __restrict__ Ch,
             const float* __restrict__ bias, const float* __restrict__ bns,
             const float* __restrict__ bnb, const _Float16* __restrict__ res,
             int M, int N, int K, int lda,
             int T_out, int Tp_in, int stride_t, int KS, int in_off,
             int gx, int gxy)
{
    constexpr int TM = MI * 32;
    __shared__ _Float16 As[TM * 64];
    __shared__ _Float16 Bs[128 * 64];

    const unsigned nwg = gridDim.x, orig = blockIdx.x;
    const unsigned q = nwg >> 3, rr_ = nwg & 7;
    const unsigned xcd = orig & 7, idx = orig >> 3;
    const unsigned wgid = (xcd < rr_) ? xcd * (q + 1) + idx
                                      : rr_ * (q + 1) + (xcd - rr_) * q + idx;
    const int by  = (int)(wgid / (unsigned)gx);
    const int bx  = (int)(wgid - (unsigned)by * (unsigned)gx);
    (void)gxy;

    const int tid  = threadIdx.x;
    const int lane = tid & 63;
    const int wid  = tid >> 6;
    const int m0   = by * TM;
    const int n0   = bx * 128;
    const int wm   = (wid >> 1) * (MI * 16);
    const int wn   = (wid & 1) * 64;

    f4 acc[MI][4];
    #pragma unroll
    for (int i = 0; i < MI; ++i)
        #pragma unroll
        for (int j = 0; j < 4; ++j)
            #pragma unroll
            for (int p = 0; p < 4; ++p) acc[i][j][p] = 0.0f;

    const int colh = (((lane & 7) ^ ((lane >> 3) & 7)) << 3);
    size_t aoff[MI];
    #pragma unroll
    for (int i = 0; i < MI; ++i) {
        int m = min(m0 + wid * (MI * 8) + i * 8 + (lane >> 3), M - 1);
        int ab = m / T_out, at = m - ab * T_out;
        aoff[i] = ((size_t)ab * Tp_in + at * stride_t + in_off) * lda + colh;
    }
    size_t boff[4];
    #pragma unroll
    for (int i = 0; i < 4; ++i)
        boff[i] = (size_t)(n0 + wid * 32 + i * 8 + (lane >> 3)) * K + colh;
    const size_t bdk = (size_t)N * K;

    const int fr  = lane & 15;
    const int grp = lane >> 4;

    for (int dk = 0; dk < KS; ++dk) {
        const size_t adk = (size_t)dk * lda;
        const size_t bdo = (size_t)dk * bdk;

        for (int k0 = 0; k0 < K; k0 += 64) {
            #pragma unroll
            for (int i = 0; i < MI; ++i)
                g2l16(A + aoff[i] + adk + k0, &As[(wid * (MI * 8) + i * 8) * 64]);
            #pragma unroll
            for (int i = 0; i < 4; ++i)
                g2l16(B + boff[i] + bdo + k0, &Bs[(wid * 32 + i * 8) * 64]);
            __syncthreads();

            #pragma unroll
            for (int kh = 0; kh < 2; ++kh) {
                const int co = (((kh * 4 + grp) ^ (fr & 7)) << 3);
                h8 af[MI], bf[4];
                #pragma unroll
                for (int mi = 0; mi < MI; ++mi)
                    af[mi] = *(const h8*)&As[(wm + mi * 16 + fr) * 64 + co];
                #pragma unroll
                for (int ni = 0; ni < 4; ++ni)
                    bf[ni] = *(const h8*)&Bs[(wn + ni * 16 + fr) * 64 + co];
                #pragma unroll
                for (int mi = 0; mi < MI; ++mi)
                    #pragma unroll
                    for (int ni = 0; ni < 4; ++ni)
                        acc[mi][ni] = __builtin_amdgcn_mfma_f32_16x16x32_f16(
                            af[mi], bf[ni], acc[mi][ni], 0, 0, 0);
            }
            __syncthreads();
        }
    }

    epilogue<EPI, OPAD, MI>(acc, lane, m0, wm, n0, wn, M, N, T_out, 0,
                            Cf, Ch, bias, bns, bnb, res, nullptr, 0);
}

// ---------------------------------------------------------------------------
// FC GEMM (R10/R11-validated gemm6): 128-wide N-tile, BK=64, ping-pong dbuf,
// ONE barrier per step. The measured-best structure for all FC GEMMs.
// ---------------------------------------------------------------------------
template<int EPI, int MI>
__global__ __launch_bounds__(256)
void gemm6_k(const _Float16* __restrict__ A, const _Float16* __restrict__ B,
             float* __restrict__ Cf, _Float16* __restrict__ Ch,
             const float* __restrict__ bias, const float* __restrict__ resf,
             int M, int N, int K, int lda,
             int gx, int gxy,
             size_t a_z, size_t b_z, size_t c_z)
{
    constexpr int TM = MI * 32;
    __shared__ _Float16 As[2][TM * 64];
    __shared__ _Float16 Bs[2][128 * 64];

    const unsigned nwg = gridDim.x, orig = blockIdx.x;
    const unsigned q = nwg >> 3, rr_ = nwg & 7;
    const unsigned xcd = orig & 7, idx = orig >> 3;
    const unsigned wgid = (xcd < rr_) ? xcd * (q + 1) + idx
                                      : rr_ * (q + 1) + (xcd - rr_) * q + idx;
    const int bz  = (int)(wgid / (unsigned)gxy);
    const int rem = (int)(wgid - (unsigned)bz * (unsigned)gxy);
    const int by  = rem / gx;
    const int bx  = rem - by * gx;

    A += (size_t)bz * a_z;
    B += (size_t)bz * b_z;

    const int tid  = threadIdx.x;
    const int lane = tid & 63;
    const int wid  = tid >> 6;
    const int m0   = by * TM;
    const int n0   = bx * 128;
    const int wm   = (wid >> 1) * (MI * 16);
    const int wn   = (wid & 1) * 64;

    f4 acc[MI][4];
    #pragma unroll
    for (int i = 0; i < MI; ++i)
        #pragma unroll
        for (int j = 0; j < 4; ++j)
            #pragma unroll
            for (int p = 0; p < 4; ++p) acc[i][j][p] = 0.0f;

    const int colh = (((lane & 7) ^ ((lane >> 3) & 7)) << 3);
    size_t aoff[MI];
    #pragma unroll
    for (int i = 0; i < MI; ++i) {
        int m = min(m0 + wid * (MI * 8) + i * 8 + (lane >> 3), M - 1);
        aoff[i] = (size_t)m * lda + colh;
    }
    size_t boff[4];
    #pragma unroll
    for (int i = 0; i < 4; ++i)
        boff[i] = (size_t)(n0 + wid * 32 + i * 8 + (lane >> 3)) * K + colh;

    const int fr  = lane & 15;
    const int grp = lane >> 4;
    const int NS  = K >> 6;

    auto stage = [&](int step, int buf) {
        const int k0 = step << 6;
        #pragma unroll
        for (int i = 0; i < MI; ++i)
            g2l16(A + aoff[i] + k0, &As[buf][(wid * (MI * 8) + i * 8) * 64]);
        #pragma unroll
        for (int i = 0; i < 4; ++i)
            g2l16(B + boff[i] + k0, &Bs[buf][(wid * 32 + i * 8) * 64]);
    };

    stage(0, 0);
    __syncthreads();

    for (int step = 0; step < NS; ++step) {
        const int cur = step & 1;
        const _Float16* As_ = As[cur];
        const _Float16* Bs_ = Bs[cur];

        const int co0 = ((grp ^ (fr & 7)) << 3);
        h8 af0[MI], bf0[4];
        #pragma unroll
        for (int mi = 0; mi < MI; ++mi)
            af0[mi] = *(const h8*)&As_[(wm + mi * 16 + fr) * 64 + co0];
        #pragma unroll
        for (int ni = 0; ni < 4; ++ni)
            bf0[ni] = *(const h8*)&Bs_[(wn + ni * 16 + fr) * 64 + co0];

        if (step + 1 < NS) stage(step + 1, cur ^ 1);

        #pragma unroll
        for (int mi = 0; mi < MI; ++mi)
            #pragma unroll
            for (int ni = 0; ni < 4; ++ni)
                acc[mi][ni] = __builtin_amdgcn_mfma_f32_16x16x32_f16(
                    af0[mi], bf0[ni], acc[mi][ni], 0, 0, 0);

        const int co1 = (((4 + grp) ^ (fr & 7)) << 3);
        h8 af1[MI], bf1[4];
        #pragma unroll
        for (int mi = 0; mi < MI; ++mi)
            af1[mi] = *(const h8*)&As_[(wm + mi * 16 + fr) * 64 + co1];
        #pragma unroll
        for (int ni = 0; ni < 4; ++ni)
            bf1[ni] = *(const h8*)&Bs_[(wn + ni * 16 + fr) * 64 + co1];
        #pragma unroll
        for (int mi = 0; mi < MI; ++mi)
            #pragma unroll
            for (int ni = 0; ni < 4; ++ni)
                acc[mi][ni] = __builtin_amdgcn_mfma_f32_16x16x32_f16(
                    af1[mi], bf1[ni], acc[mi][ni], 0, 0, 0);

        __syncthreads();
    }

    epilogue<EPI, false, MI>(acc, lane, m0, wm, n0, wn, M, N, 0, bz,
                             Cf, Ch, bias, nullptr, nullptr, nullptr, resf, c_z);
}

// ------------------------- small helper kernels ----------------------------

__global__ void f2h8_k(const float* __restrict__ in, _Float16* __restrict__ out,
                       long n8)
{
    long i = (long)blockIdx.x * blockDim.x + threadIdx.x;
    if (i >= n8) return;
    f4 a = ((const f4*)in)[2 * i];
    f4 b = ((const f4*)in)[2 * i + 1];
    h8 o;
    #pragma unroll
    for (int j = 0; j < 4; ++j) { o[j] = (_Float16)a[j]; o[4 + j] = (_Float16)b[j]; }
    ((h8*)out)[i] = o;
}

__global__ void f2h_pad_k(const float* __restrict__ in, _Float16* __restrict__ out)
{
    long i = (long)blockIdx.x * blockDim.x + threadIdx.x;
    if (i >= (long)B_ * 398 * FIN) return;
    int  c = (int)(i % FIN);
    long r = i / FIN;
    int  t = (int)(r % 398);
    int  b = (int)(r / 398);
    float v = (t == 0 || t == 397) ? 0.0f
            : in[((long)b * T0 + (t - 1)) * FIN + c];
    out[i] = (_Float16)v;
}

__global__ void zero_pad_k(_Float16* __restrict__ buf, int Tp, int C)
{
    long i = (long)blockIdx.x * blockDim.x + threadIdx.x;
    if (i >= (long)B_ * 2 * C) return;
    int  c = (int)(i % C);
    long r = i / C;
    int  hi = (int)(r % 2);
    int  b  = (int)(r / 2);
    buf[((size_t)b * Tp + (hi ? Tp - 1 : 0)) * C + c] = (_Float16)0.0f;
}

__global__ void pack_qkv_k(const float* __restrict__ wq, const float* __restrict__ wk,
                           const float* __restrict__ wv, _Float16* __restrict__ out)
{
    long i = (long)blockIdx.x * blockDim.x + threadIdx.x;
    if (i >= (long)NL * 2304 * DM) return;
    int  f = (int)(i % DM);
    long r = i / DM;
    int  n = (int)(r % 2304);
    int  l = (int)(r / 2304);
    int  s = n / DM, hn = n % DM, h = hn / DQ, a = hn % DQ;
    const float* src = (s == 0) ? wq : ((s == 1) ? wk : wv);
    out[i] = (_Float16)src[(((long)l * NHEAD + h) * DM + f) * DQ + a];
}

__global__ void pack_wo_k(const float* __restrict__ wo, _Float16* __restrict__ out)
{
    long i = (long)blockIdx.x * blockDim.x + threadIdx.x;
    if (i >= (long)NL * DM * DM) return;
    int  ha = (int)(i % DM);
    long r  = i / DM;
    int  f  = (int)(r % DM);
    int  l  = (int)(r / DM);
    int  h = ha / DQ, a = ha % DQ;
    out[i] = (_Float16)wo[(((long)l * NHEAD + h) * DQ + a) * DM + f];
}

__global__ void pack_conv_k(const float* __restrict__ w, _Float16* __restrict__ out,
                            int Cout, int Cin, int KS)
{
    long i = (long)blockIdx.x * blockDim.x + threadIdx.x;
    if (i >= (long)Cout * Cin * KS) return;
    int  ci = (int)(i % Cin);
    long r  = i / Cin;
    int  co = (int)(r % Cout);
    int  dk = (int)(r / Cout);
    out[i] = (_Float16)w[((long)co * Cin + ci) * KS + dk];
}

__global__ void pack_rel_k(const float* __restrict__ rel, _Float16* __restrict__ out)
{
    long i = (long)blockIdx.x * blockDim.x + threadIdx.x;
    if (i >= (long)NL * NHEAD * POSN * RELK) return;
    int  k = (int)(i & (RELK - 1));
    long r = i >> 7;
    int  n = (int)(r & (POSN - 1));
    long r2 = r >> 8;
    int  h = (int)(r2 & (NHEAD - 1));
    int  l = (int)(r2 >> 3);
    float v = 0.0f;
    if (n < NREL && k < DQ)
        v = rel[(((long)l * NHEAD + h) * NREL + n) * DQ + k] * 0.10206207261596575f;
    out[i] = (_Float16)v;
}

__global__ void concat_k(const float* __restrict__ xlin, const float* __restrict__ cls,
                         float* __restrict__ xf, _Float16* __restrict__ xh)
{
    long i = (long)blockIdx.x * blockDim.x + threadIdx.x;
    if (i >= (long)MSEQ * DM) return;
    int  c = (int)(i % DM);
    long m = i / DM;
    int  b = (int)(m / L_), t = (int)(m % L_);
    float v = (t == 0) ? cls[c] : xlin[((long)b * (L_ - 1) + (t - 1)) * DM + c];
    xf[i] = v;
    xh[i] = (_Float16)v;
}

// LayerNorm over a pre-summed input (residual fused into GEMM epilogue)
__global__ __launch_bounds__(256)
void ln_k(const float* __restrict__ sIn,
          const float* __restrict__ g, const float* __restrict__ bb,
          float* __restrict__ xo, _Float16* __restrict__ xh)
{
    long row = blockIdx.x;
    const float* sr = sIn + row * DM;
    float v[3];
    float s = 0.0f;
    #pragma unroll
    for (int k = 0; k < 3; ++k) {
        int c = threadIdx.x + 256 * k;
        v[k] = sr[c];
        s += v[k];
    }
    __shared__ float red[8];
    #pragma unroll
    for (int o = 32; o; o >>= 1) s += __shfl_xor(s, o, 64);
    int w = threadIdx.x >> 6, lane = threadIdx.x & 63;
    if (lane == 0) red[w] = s;
    __syncthreads();
    s = red[0] + red[1] + red[2] + red[3];
    float mean = s * (1.0f / DM);
    float vs = 0.0f;
    #pragma unroll
    for (int k = 0; k < 3; ++k) { float t = v[k] - mean; vs += t * t; }
    #pragma unroll
    for (int o = 32; o; o >>= 1) vs += __shfl_xor(vs, o, 64);
    if (lane == 0) red[4 + w] = vs;
    __syncthreads();
    vs = red[4] + red[5] + red[6] + red[7];
    float rstd = rsqrtf(vs * (1.0f / DM) + 1e-5f);
    #pragma unroll
    for (int k = 0; k < 3; ++k) {
        int c = threadIdx.x + 256 * k;
        float y = (v[k] - mean) * rstd * g[c] + bb[c];
        xo[row * DM + c] = y;
        xh[row * DM + c] = (_Float16)y;
    }
}

// MFMA fused attention (unchanged — validated rounds 2-13).
constexpr int LP = 128;
constexpr int KP = 104;
constexpr int PP = 136;

__global__ __launch_bounds__(256)
void attn_k(const _Float16* __restrict__ qkv, const _Float16* __restrict__ pos,
            _Float16* __restrict__ o)
{
    __shared__ __align__(16) char smem[60928];
    _Float16* Ks = (_Float16*)smem;
    _Float16* Ps = (_Float16*)smem;
    _Float16* Vt = (_Float16*)(smem + 34816);

    const int h = blockIdx.x, b = blockIdx.y;
    const int tid = threadIdx.x, lane = tid & 63, w = tid >> 6;
    const _Float16* base = qkv + (size_t)b * L_ * 2304 + h * DQ;
    const float qscale = 0.10206207261596575f;

    {
        int row = tid >> 1;
        int c0  = (tid & 1) * 48;
        const bool real = row < L_;
        const _Float16* krow = base + 768 + (size_t)row * 2304;
        #pragma unroll
        for (int q = 0; q < 6; ++q) {
            int c = c0 + q * 8;
            h8 kv;
            #pragma unroll
            for (int e = 0; e < 8; ++e) kv[e] = (_Float16)0.0f;
            if (real) kv = *(const h8*)(krow + c);
            *(h8*)&Ks[row * KP + c] = kv;
        }
        for (int idx = tid; idx < DQ * LP; idx += 256) {
            int a = idx % DQ, j = idx / DQ;
            _Float16 v = (_Float16)0.0f;
            if (j < L_) v = base[1536 + (size_t)j * 2304 + a];
            Vt[a * PP + j] = v;
        }
    }
    __syncthreads();

    const int fr = lane & 15;
    const int fk = (lane >> 4) * 8;
    const int rbase = w * 32 + ((lane >> 4) << 2);

    f4 acc[2][8];
    #pragma unroll
    for (int mi = 0; mi < 2; ++mi)
        #pragma unroll
        for (int ni = 0; ni < 8; ++ni)
            #pragma unroll
            for (int q = 0; q < 4; ++q) acc[mi][ni][q] = 0.0f;

    #pragma unroll
    for (int k0 = 0; k0 < DQ; k0 += 32) {
        h8 a0 = *(const h8*)(base + (size_t)(w * 32 + fr) * 2304 + k0 + fk);
        h8 a1 = *(const h8*)(base + (size_t)(w * 32 + 16 + fr) * 2304 + k0 + fk);
        #pragma unroll
        for (int ni = 0; ni < 8; ++ni) {
            h8 bv = *(const h8*)&Ks[(ni * 16 + fr) * KP + k0 + fk];
            acc[0][ni] = __builtin_amdgcn_mfma_f32_16x16x32_f16(a0, bv, acc[0][ni], 0, 0, 0);
            acc[1][ni] = __builtin_amdgcn_mfma_f32_16x16x32_f16(a1, bv, acc[1][ni], 0, 0, 0);
        }
    }

    const _Float16* posb = pos + ((size_t)h * MSEQ + (size_t)b * L_) * POSN;
    #pragma unroll
    for (int mi = 0; mi < 2; ++mi)
        #pragma unroll
        for (int r = 0; r < 4; ++r) {
            int i = rbase + mi * 16 + r;
            float s[8];
            #pragma unroll
            for (int ni = 0; ni < 8; ++ni) {
                int j = ni * 16 + fr;
                float v = -3.0e38f;
                if (i < L_ && j < L_)
                    v = acc[mi][ni][r] * qscale
                      + (float)posb[(size_t)i * POSN + (j - i + (L_ - 1))];
                s[ni] = v;
            }
            float m = s[0];
            #pragma unroll
            for (int ni = 1; ni < 8; ++ni) m = fmaxf(m, s[ni]);
            #pragma unroll
            for (int msk = 1; msk < 16; msk <<= 1) m = fmaxf(m, __shfl_xor(m, msk, 64));
            float sum = 0.0f;
            #pragma unroll
            for (int ni = 0; ni < 8; ++ni) { s[ni] = __expf(s[ni] - m); sum += s[ni]; }
            #pragma unroll
            for (int msk = 1; msk < 16; msk <<= 1) sum += __shfl_xor(sum, msk, 64);
            float inv = 1.0f / sum;
            #pragma unroll
            for (int ni = 0; ni < 8; ++ni) acc[mi][ni][r] = s[ni] * inv;
        }

    __syncthreads();

    #pragma unroll
    for (int mi = 0; mi < 2; ++mi)
        #pragma unroll
        for (int r = 0; r < 4; ++r) {
            int i = rbase + mi * 16 + r;
            #pragma unroll
            for (int ni = 0; ni < 8; ++ni)
                Ps[i * PP + ni * 16 + fr] = (_Float16)acc[mi][ni][r];
        }
    __syncthreads();

    f4 acc2[2][6];
    #pragma unroll
    for (int mi = 0; mi < 2; ++mi)
        #pragma unroll
        for (int ni = 0; ni < 6; ++ni)
            #pragma unroll
            for (int q = 0; q < 4; ++q) acc2[mi][ni][q] = 0.0f;

    #pragma unroll
    for (int k0 = 0; k0 < LP; k0 += 32) {
        h8 a0 = *(const h8*)&Ps[(w * 32 + fr) * PP + k0 + fk];
        h8 a1 = *(const h8*)&Ps[(w * 32 + 16 + fr) * PP + k0 + fk];
        #pragma unroll
        for (int ni = 0; ni < 6; ++ni) {
            h8 bv = *(const h8*)&Vt[(ni * 16 + fr) * PP + k0 + fk];
            acc2[0][ni] = __builtin_amdgcn_mfma_f32_16x16x32_f16(a0, bv, acc2[0][ni], 0, 0, 0);
            acc2[1][ni] = __builtin_amdgcn_mfma_f32_16x16x32_f16(a1, bv, acc2[1][ni], 0, 0, 0);
        }
    }

    _Float16* ob = o + (size_t)b * L_ * DM + h * DQ;
    #pragma unroll
    for (int mi = 0; mi < 2; ++mi)
        #pragma unroll
        for (int r = 0; r < 4; ++r) {
            int i = rbase + mi * 16 + r;
            if (i < L_) {
                #pragma unroll
                for (int ni = 0; ni < 6; ++ni)
                    ob[(size_t)i * DM + ni * 16 + fr] = (_Float16)acc2[mi][ni][r];
            }
        }
}

__global__ __launch_bounds__(256)
void out_k(const float* __restrict__ xseq, const float* __restrict__ w,
           const float* __restrict__ bias, float* __restrict__ out)
{
    __shared__ float xs[DM];
    int b = blockIdx.x;
    for (int c = threadIdx.x; c < DM; c += 256) xs[c] = xseq[(size_t)b * L_ * DM + c];
    __syncthreads();
    int n = threadIdx.x;
    const f4* wr = (const f4*)(w + (size_t)n * DM);
    float acc = 0.0f;
    #pragma unroll 4
    for (int k4 = 0; k4 < DM / 4; ++k4) {
        f4 wv = wr[k4];
        f4 xv = *(const f4*)&xs[k4 * 4];
        acc += wv[0]*xv[0] + wv[1]*xv[1] + wv[2]*xv[2] + wv[3]*xv[3];
    }
    out[(size_t)b * 256 + n] = acc + bias[n];
}

} // anonymous namespace

// ---------------------------------------------------------------------------
extern "C" void kernel_launch(void* const* d_in, const int* in_sizes, int n_in,
                              void* d_out, int out_size, void* d_ws, size_t ws_size,
                              hipStream_t stream)
{
    (void)in_sizes; (void)n_in; (void)out_size; (void)ws_size;

    const float* x_raw   = (const float*)d_in[0];
    const float* rb1_c1w = (const float*)d_in[1];
    const float* rb1_c1b = (const float*)d_in[2];
    const float* rb1_s1  = (const float*)d_in[3];
    const float* rb1_b1  = (const float*)d_in[4];
    const float* rb1_c2w = (const float*)d_in[5];
    const float* rb1_c2b = (const float*)d_in[6];
    const float* rb1_s2  = (const float*)d_in[7];
    const float* rb1_b2  = (const float*)d_in[8];
    const float* rb1_crw = (const float*)d_in[9];
    const float* rb1_crb = (const float*)d_in[10];
    const float* rb1_sr  = (const float*)d_in[11];
    const float* rb1_br  = (const float*)d_in[12];
    const float* rb2_c1w = (const float*)d_in[13];
    const float* rb2_c1b = (const float*)d_in[14];
    const float* rb2_s1  = (const float*)d_in[15];
    const float* rb2_b1  = (const float*)d_in[16];
    const float* rb2_c2w = (const float*)d_in[17];
    const float* rb2_c2b = (const float*)d_in[18];
    const float* rb2_s2  = (const float*)d_in[19];
    const float* rb2_b2  = (const float*)d_in[20];
    const float* rb2_crw = (const float*)d_in[21];
    const float* rb2_crb = (const float*)d_in[22];
    const float* rb2_sr  = (const float*)d_in[23];
    const float* rb2_br  = (const float*)d_in[24];
    const float* w_in_w  = (const float*)d_in[25];
    const float* w_in_b  = (const float*)d_in[26];
    const float* cls     = (const float*)d_in[27];
    const float* wq      = (const float*)d_in[28];
    const float* wk      = (const float*)d_in[29];
    const float* wv      = (const float*)d_in[30];
    const float* wo      = (const float*)d_in[31];
    const float* rel     = (const float*)d_in[32];
    const float* ln1g    = (const float*)d_in[33];
    const float* ln1b    = (const float*)d_in[34];
    const float* ln2g    = (const float*)d_in[35];
    const float* ln2b    = (const float*)d_in[36];
    const float* ff1w    = (const float*)d_in[37];
    const float* ff1b    = (const float*)d_in[38];
    const float* ff2w    = (const float*)d_in[39];
    const float* ff2b    = (const float*)d_in[40];
    const float* w_out_w = (const float*)d_in[41];
    const float* w_out_b = (const float*)d_in[42];

    char* base = (char*)d_ws;
    size_t off = 0;
    auto carve = [&](size_t bytes) -> char* {
        char* p = base + off;
        off = (off + bytes + 255) & ~(size_t)255;
        return p;
    };
    _Float16* w_in_h = (_Float16*)carve((size_t)589824 * 2);
    _Float16* qkvw   = (_Float16*)carve((size_t)10616832 * 2);
    _Float16* wow    = (_Float16*)carve((size_t)3538944 * 2);
    _Float16* ff1h   = (_Float16*)carve((size_t)14155776 * 2);
    _Float16* ff2h   = (_Float16*)carve((size_t)14155776 * 2);
    _Float16* relh   = (_Float16*)carve((size_t)NL * NHEAD * POSN * RELK * 2);
    _Float16* cw11   = (_Float16*)carve((size_t)294912 * 2);
    _Float16* cw12   = (_Float16*)carve((size_t)1769472 * 2);
    _Float16* cw1r   = (_Float16*)carve((size_t)98304 * 2);
    _Float16* cw21   = (_Float16*)carve((size_t)1769472 * 2);
    _Float16* cw22   = (_Float16*)carve((size_t)1769472 * 2);
    _Float16* cw2r   = (_Float16*)carve((size_t)589824 * 2);
    _Float16* xrawp  = (_Float16*)carve((size_t)B_ * 398 * FIN * 2);
    float*    xseq_f = (float*)carve((size_t)4915200 * 4);
    _Float16* xseq_h = (_Float16*)carve((size_t)4915200 * 2);
    _Float16* qkvb   = (_Float16*)carve((size_t)14745600 * 2);
    _Float16* ohb    = (_Float16*)carve((size_t)4915200 * 2);
    float*    af     = (float*)carve((size_t)4915200 * 4);
    char*     hhreg  = carve((size_t)19660800 * 2);
    float*    yf     = (float*)carve((size_t)4915200 * 4);
    // phase-overlapped aliases (strictly sequential producer->consumer):
    _Float16* h1_rb1 = qkvb;                 // [64][200][768] padded
    _Float16* r_rb1h = (_Float16*)hhreg;     // [12672][768] f16 residual
    _Float16* out1   = (_Float16*)af;        // [64][200][768] padded
    _Float16* h1_rb2 = (_Float16*)xseq_f;    // [64][101][768] padded
    _Float16* r_rb2h = (_Float16*)yf;        // [6336][768] f16 residual
    _Float16* out2   = ohb;                  // [6336][768] plain
    float*    xlin   = (float*)hhreg;
    _Float16* posh   = (_Float16*)hhreg;
    _Float16* ffh    = (_Float16*)hhreg;

    dim3 blk(256, 1, 1);
    auto grd = [](long n) { return dim3((unsigned)((n + 255) / 256), 1, 1); };
    #define NWG(M, N, TM, GZ) dim3((unsigned)(((N) / 128) * (((M) + (TM) - 1) / (TM)) * (GZ)), 1, 1)
    #define GXY(M, N, TM) ((N) / 128), (((N) / 128) * (((M) + (TM) - 1) / (TM)))

    // ---- weight conversion / packing ----
    f2h_pad_k<<<grd((long)B_ * 398 * FIN), blk, 0, stream>>>(x_raw, xrawp);
    zero_pad_k<<<grd((long)B_ * 2 * DM), blk, 0, stream>>>(h1_rb1, 200, DM);
    zero_pad_k<<<grd((long)B_ * 2 * DM), blk, 0, stream>>>(out1, 200, DM);
    zero_pad_k<<<grd((long)B_ * 2 * DM), blk, 0, stream>>>(h1_rb2, 101, DM);
    f2h8_k<<<grd(589824 / 8), blk, 0, stream>>>(w_in_w, w_in_h, 589824 / 8);
    f2h8_k<<<grd(14155776 / 8), blk, 0, stream>>>(ff1w, ff1h, 14155776 / 8);
    f2h8_k<<<grd(14155776 / 8), blk, 0, stream>>>(ff2w, ff2h, 14155776 / 8);
    pack_rel_k<<<grd((long)NL * NHEAD * POSN * RELK), blk, 0, stream>>>(rel, relh);
    pack_qkv_k<<<grd((long)NL * 2304 * DM), blk, 0, stream>>>(wq, wk, wv, qkvw);
    pack_wo_k<<<grd((long)NL * DM * DM), blk, 0, stream>>>(wo, wow);
    pack_conv_k<<<grd(294912), blk, 0, stream>>>(rb1_c1w, cw11, DM, FIN, 3);
    pack_conv_k<<<grd(1769472), blk, 0, stream>>>(rb1_c2w, cw12, DM, DM, 3);
    pack_conv_k<<<grd(98304), blk, 0, stream>>>(rb1_crw, cw1r, DM, FIN, 1);
    pack_conv_k<<<grd(1769472), blk, 0, stream>>>(rb2_c1w, cw21, DM, DM, 3);
    pack_conv_k<<<grd(1769472), blk, 0, stream>>>(rb2_c2w, cw22, DM, DM, 3);
    pack_conv_k<<<grd(589824), blk, 0, stream>>>(rb2_crw, cw2r, DM, DM, 1);

    // ---- resblock 1 (T 396 -> 198); MI=4 ----
    gemm5_k<EPI_CONV_BN_H, false, 4><<<NWG(M1, DM, 128, 1), blk, 0, stream>>>(
        xrawp, cw1r, nullptr, r_rb1h, rb1_crb, rb1_sr, rb1_br, nullptr,
        M1, DM, FIN, FIN, T1, 398, 2, 1, 1, GXY(M1, DM, 128));
    gemm5_k<EPI_CONV_RELU_H, true, 4><<<NWG(M1, DM, 128, 1), blk, 0, stream>>>(
        xrawp, cw11, nullptr, h1_rb1, rb1_c1b, rb1_s1, rb1_b1, nullptr,
        M1, DM, FIN, FIN, T1, 398, 2, 3, 0, GXY(M1, DM, 128));
    gemm5_k<EPI_CONV_ADD_RELU_H, true, 4><<<NWG(M1, DM, 128, 1), blk, 0, stream>>>(
        h1_rb1, cw12, nullptr, out1, rb1_c2b, rb1_s2, rb1_b2, r_rb1h,
        M1, DM, DM, DM, T1, 200, 1, 3, 0, GXY(M1, DM, 128));

    // ---- resblock 2 (T 198 -> 99); MI=2 ----
    gemm5_k<EPI_CONV_BN_H, false, 2><<<NWG(M2, DM, 64, 1), blk, 0, stream>>>(
        out1, cw2r, nullptr, r_rb2h, rb2_crb, rb2_sr, rb2_br, nullptr,
        M2, DM, DM, DM, T2, 200, 2, 1, 1, GXY(M2, DM, 64));
    gemm5_k<EPI_CONV_RELU_H, true, 2><<<NWG(M2, DM, 64, 1), blk, 0, stream>>>(
        out1, cw21, nullptr, h1_rb2, rb2_c1b, rb2_s1, rb2_b1, nullptr,
        M2, DM, DM, DM, T2, 200, 2, 3, 0, GXY(M2, DM, 64));
    gemm5_k<EPI_CONV_ADD_RELU_H, false, 2><<<NWG(M2, DM, 64, 1), blk, 0, stream>>>(
        h1_rb2, cw22, nullptr, out2, rb2_c2b, rb2_s2, rb2_b2, r_rb2h,
        M2, DM, DM, DM, T2, 101, 1, 3, 0, GXY(M2, DM, 64));

    // ---- input projection + cls concat ----
    gemm6_k<EPI_F32, 2><<<NWG(M2, DM, 64, 1), blk, 0, stream>>>(
        out2, w_in_h, xlin, nullptr, w_in_b, nullptr,
        M2, DM, DM, DM, GXY(M2, DM, 64), 0, 0, 0);
    concat_k<<<grd((long)MSEQ * DM), blk, 0, stream>>>(xlin, cls, xseq_f, xseq_h);

    // ---- transformer layers ----
    for (int l = 0; l < NL; ++l) {
        gemm6_k<EPI_H, 4><<<NWG(MSEQ, 2304, 128, 1), blk, 0, stream>>>(
            xseq_h, qkvw + (size_t)l * 2304 * DM, nullptr, qkvb, nullptr, nullptr,
            MSEQ, 2304, DM, DM, GXY(MSEQ, 2304, 128), 0, 0, 0);
        gemm6_k<EPI_H, 4><<<NWG(MSEQ, POSN, 128, NHEAD), blk, 0, stream>>>(
            qkvb, relh + (size_t)l * NHEAD * POSN * RELK, nullptr, posh, nullptr, nullptr,
            MSEQ, POSN, RELK, 2304, GXY(MSEQ, POSN, 128),
            (size_t)DQ, (size_t)POSN * RELK, (size_t)MSEQ * POSN);
        attn_k<<<dim3(NHEAD, B_, 1), blk, 0, stream>>>(qkvb, posh, ohb);
        // wo: delta + residual fused (af = xseq_f + attn_out @ wo^T)
        gemm6_k<EPI_ADD_F32, 2><<<NWG(MSEQ, DM, 64, 1), blk, 0, stream>>>(
            ohb, wow + (size_t)l * DM * DM, af, nullptr, nullptr, xseq_f,
            MSEQ, DM, DM, DM, GXY(MSEQ, DM, 64), 0, 0, 0);
        ln_k<<<dim3(MSEQ), blk, 0, stream>>>(af, ln1g + l * DM, ln1b + l * DM,
                                             xseq_f, xseq_h);
        gemm6_k<EPI_RELU_H, 4><<<NWG(MSEQ, DFF, 128, 1), blk, 0, stream>>>(
            xseq_h, ff1h + (size_t)l * DFF * DM, nullptr, ffh, ff1b + l * DFF, nullptr,
            MSEQ, DFF, DM, DM, GXY(MSEQ, DFF, 128), 0, 0, 0);
        // ff2: delta + residual fused (yf = xseq_f + relu(ff1) @ ff2^T + b)
        gemm6_k<EPI_ADD_F32, 2><<<NWG(MSEQ, DM, 64, 1), blk, 0, stream>>>(
            ffh, ff2h + (size_t)l * DM * DFF, yf, nullptr, ff2b + l * DM, xseq_f,
            MSEQ, DM, DFF, DFF, GXY(MSEQ, DM, 64), 0, 0, 0);
        ln_k<<<dim3(MSEQ), blk, 0, stream>>>(yf, ln2g + l * DM, ln2b + l * DM,
                                             xseq_f, xseq_h);
    }

    out_k<<<dim3(B_), blk, 0, stream>>>(xseq_f, w_out_w, w_out_b, (float*)d_out);
    #undef NWG
    #undef GXY
}

// Round 15
// 1941.687 us; speedup vs baseline: 1.2789x; 1.0576x over previous
//
#include <hip/hip_runtime.h>

typedef _Float16 h8 __attribute__((ext_vector_type(8)));
typedef float f4 __attribute__((ext_vector_type(4)));

namespace {

constexpr int DM   = 768;
constexpr int NHEAD= 8;
constexpr int DQ   = 96;
constexpr int DFF  = 3072;
constexpr int NL   = 6;
constexpr int B_   = 64;
constexpr int T0   = 396, T1 = 198, T2 = 99;
constexpr int FIN  = 128;
constexpr int L_   = 100;
constexpr int MSEQ = B_ * L_;    // 6400
constexpr int M1   = B_ * T1;    // 12672
constexpr int M2   = B_ * T2;    // 6336
constexpr int NREL = 201;
constexpr int POSN = 256;        // padded 199 -> 256
constexpr int RELK = 128;        // padded K for pos GEMM (96 -> 128)

enum { EPI_F32 = 0, EPI_RELU_H, EPI_H, EPI_CONV_BN_H, EPI_CONV_RELU_H, EPI_CONV_ADD_RELU_H };

__device__ __forceinline__ void g2l16(const _Float16* g, _Float16* l)
{
    __builtin_amdgcn_global_load_lds(
        (const __attribute__((address_space(1))) unsigned int*)g,
        (__attribute__((address_space(3))) unsigned int*)l,
        16, 0, 0);
}

// ---------------------------------------------------------------------------
// Shared epilogue. C/D mapping: col = lane&15, row = (lane>>4)*4 + reg.
// ---------------------------------------------------------------------------
template<int EPI, bool OPAD, int MI>
__device__ __forceinline__ void epilogue(
    f4 (&acc)[MI][4], int lane, int m0, int wm, int n0, int wn,
    int M, int N, int T_out, int bz,
    float* Cf, _Float16* Ch, const float* bias, const float* bns,
    const float* bnb, const _Float16* res, size_t c_z)
{
    const int frc = lane & 15;
    const int fq4 = (lane >> 4) * 4;
    float*    Cfo = Cf ? Cf + (size_t)bz * c_z : nullptr;
    _Float16* Cho = Ch ? Ch + (size_t)bz * c_z : nullptr;
    #pragma unroll
    for (int mi = 0; mi < MI; ++mi)
        #pragma unroll
        for (int ni = 0; ni < 4; ++ni)
            #pragma unroll
            for (int r = 0; r < 4; ++r) {
                int row = m0 + wm + mi * 16 + fq4 + r;
                int col = n0 + wn + ni * 16 + frc;
                if (row >= M) continue;
                float v = acc[mi][ni][r];
                size_t roff;
                if (OPAD) {
                    int ab = row / T_out, at = row - ab * T_out;
                    roff = ((size_t)ab * (T_out + 2) + at + 1) * N + col;
                } else {
                    roff = (size_t)row * N + col;
                }
                if (EPI == EPI_F32) {
                    if (bias) v += bias[col];
                    Cfo[roff] = v;
                } else if (EPI == EPI_RELU_H) {
                    if (bias) v += bias[col];
                    Cho[roff] = (_Float16)fmaxf(v, 0.0f);
                } else if (EPI == EPI_H) {
                    Cho[roff] = (_Float16)v;
                } else if (EPI == EPI_CONV_BN_H) {
                    v = bns[col] * (v + bias[col]) + bnb[col];
                    Cho[roff] = (_Float16)v;
                } else if (EPI == EPI_CONV_RELU_H) {
                    v = bns[col] * (v + bias[col]) + bnb[col];
                    Cho[roff] = (_Float16)fmaxf(v, 0.0f);
                } else { // EPI_CONV_ADD_RELU_H (f16 residual)
                    v = bns[col] * (v + bias[col]) + bnb[col]
                      + (float)res[(size_t)row * N + col];
                    Cho[roff] = (_Float16)fmaxf(v, 0.0f);
                }
            }
}

// ---------------------------------------------------------------------------
// CONV GEMM (R6-validated gemm5 structure): BK=64, single-buffer, 2-barrier,
// 32KB LDS -> 3 blocks/CU. Best measured structure for the grid-limited convs.
// ---------------------------------------------------------------------------
template<int EPI, bool OPAD, int MI>
__global__ __launch_bounds__(256)
void gemm5_k(const _Float16* __restrict__ A, const _Float16* __restrict__ B,
             float* __restrict__ Cf, _Float16* __restrict__ Ch,
             const float* __restrict__ bias, const float* __restrict__ bns,
             const float* __restrict__ bnb, const _Float16* __restrict__ res,
             int M, int N, int K, int lda,
             int T_out, int Tp_in, int stride_t, int KS, int in_off,
             int gx, int gxy)
{
    constexpr int TM = MI * 32;
    __shared__ _Float16 As[TM * 64];
    __shared__ _Float16 Bs[128 * 64];

    const unsigned nwg = gridDim.x, orig = blockIdx.x;
    const unsigned q = nwg >> 3, rr_ = nwg & 7;
    const unsigned xcd = orig & 7, idx = orig >> 3;
    const unsigned wgid = (xcd < rr_) ? xcd * (q + 1) + idx
                                      : rr_ * (q + 1) + (xcd - rr_) * q + idx;
    const int by  = (int)(wgid / (unsigned)gx);
    const int bx  = (int)(wgid - (unsigned)by * (unsigned)gx);
    (void)gxy;

    const int tid  = threadIdx.x;
    const int lane = tid & 63;
    const int wid  = tid >> 6;
    const int m0   = by * TM;
    const int n0   = bx * 128;
    const int wm   = (wid >> 1) * (MI * 16);
    const int wn   = (wid & 1) * 64;

    f4 acc[MI][4];
    #pragma unroll
    for (int i = 0; i < MI; ++i)
        #pragma unroll
        for (int j = 0; j < 4; ++j)
            #pragma unroll
            for (int p = 0; p < 4; ++p) acc[i][j][p] = 0.0f;

    const int colh = (((lane & 7) ^ ((lane >> 3) & 7)) << 3);
    size_t aoff[MI];
    #pragma unroll
    for (int i = 0; i < MI; ++i) {
        int m = min(m0 + wid * (MI * 8) + i * 8 + (lane >> 3), M - 1);
        int ab = m / T_out, at = m - ab * T_out;
        aoff[i] = ((size_t)ab * Tp_in + at * stride_t + in_off) * lda + colh;
    }
    size_t boff[4];
    #pragma unroll
    for (int i = 0; i < 4; ++i)
        boff[i] = (size_t)(n0 + wid * 32 + i * 8 + (lane >> 3)) * K + colh;
    const size_t bdk = (size_t)N * K;

    const int fr  = lane & 15;
    const int grp = lane >> 4;

    for (int dk = 0; dk < KS; ++dk) {
        const size_t adk = (size_t)dk * lda;
        const size_t bdo = (size_t)dk * bdk;

        for (int k0 = 0; k0 < K; k0 += 64) {
            #pragma unroll
            for (int i = 0; i < MI; ++i)
                g2l16(A + aoff[i] + adk + k0, &As[(wid * (MI * 8) + i * 8) * 64]);
            #pragma unroll
            for (int i = 0; i < 4; ++i)
                g2l16(B + boff[i] + bdo + k0, &Bs[(wid * 32 + i * 8) * 64]);
            __syncthreads();

            #pragma unroll
            for (int kh = 0; kh < 2; ++kh) {
                const int co = (((kh * 4 + grp) ^ (fr & 7)) << 3);
                h8 af[MI], bf[4];
                #pragma unroll
                for (int mi = 0; mi < MI; ++mi)
                    af[mi] = *(const h8*)&As[(wm + mi * 16 + fr) * 64 + co];
                #pragma unroll
                for (int ni = 0; ni < 4; ++ni)
                    bf[ni] = *(const h8*)&Bs[(wn + ni * 16 + fr) * 64 + co];
                #pragma unroll
                for (int mi = 0; mi < MI; ++mi)
                    #pragma unroll
                    for (int ni = 0; ni < 4; ++ni)
                        acc[mi][ni] = __builtin_amdgcn_mfma_f32_16x16x32_f16(
                            af[mi], bf[ni], acc[mi][ni], 0, 0, 0);
            }
            __syncthreads();
        }
    }

    epilogue<EPI, OPAD, MI>(acc, lane, m0, wm, n0, wn, M, N, T_out, 0,
                            Cf, Ch, bias, bns, bnb, res, 0);
}

// ---------------------------------------------------------------------------
// FC GEMM (R10-validated gemm6): BK=64, ping-pong dbuf, ONE barrier/step.
// ---------------------------------------------------------------------------
template<int EPI, int MI>
__global__ __launch_bounds__(256)
void gemm6_k(const _Float16* __restrict__ A, const _Float16* __restrict__ B,
             float* __restrict__ Cf, _Float16* __restrict__ Ch,
             const float* __restrict__ bias,
             int M, int N, int K, int lda,
             int gx, int gxy,
             size_t a_z, size_t b_z, size_t c_z)
{
    constexpr int TM = MI * 32;
    __shared__ _Float16 As[2][TM * 64];
    __shared__ _Float16 Bs[2][128 * 64];

    const unsigned nwg = gridDim.x, orig = blockIdx.x;
    const unsigned q = nwg >> 3, rr_ = nwg & 7;
    const unsigned xcd = orig & 7, idx = orig >> 3;
    const unsigned wgid = (xcd < rr_) ? xcd * (q + 1) + idx
                                      : rr_ * (q + 1) + (xcd - rr_) * q + idx;
    const int bz  = (int)(wgid / (unsigned)gxy);
    const int rem = (int)(wgid - (unsigned)bz * (unsigned)gxy);
    const int by  = rem / gx;
    const int bx  = rem - by * gx;

    A += (size_t)bz * a_z;
    B += (size_t)bz * b_z;

    const int tid  = threadIdx.x;
    const int lane = tid & 63;
    const int wid  = tid >> 6;
    const int m0   = by * TM;
    const int n0   = bx * 128;
    const int wm   = (wid >> 1) * (MI * 16);
    const int wn   = (wid & 1) * 64;

    f4 acc[MI][4];
    #pragma unroll
    for (int i = 0; i < MI; ++i)
        #pragma unroll
        for (int j = 0; j < 4; ++j)
            #pragma unroll
            for (int p = 0; p < 4; ++p) acc[i][j][p] = 0.0f;

    const int colh = (((lane & 7) ^ ((lane >> 3) & 7)) << 3);
    size_t aoff[MI];
    #pragma unroll
    for (int i = 0; i < MI; ++i) {
        int m = min(m0 + wid * (MI * 8) + i * 8 + (lane >> 3), M - 1);
        aoff[i] = (size_t)m * lda + colh;
    }
    size_t boff[4];
    #pragma unroll
    for (int i = 0; i < 4; ++i)
        boff[i] = (size_t)(n0 + wid * 32 + i * 8 + (lane >> 3)) * K + colh;

    const int fr  = lane & 15;
    const int grp = lane >> 4;
    const int NS  = K >> 6;

    auto stage = [&](int step, int buf) {
        const int k0 = step << 6;
        #pragma unroll
        for (int i = 0; i < MI; ++i)
            g2l16(A + aoff[i] + k0, &As[buf][(wid * (MI * 8) + i * 8) * 64]);
        #pragma unroll
        for (int i = 0; i < 4; ++i)
            g2l16(B + boff[i] + k0, &Bs[buf][(wid * 32 + i * 8) * 64]);
    };

    stage(0, 0);
    __syncthreads();

    for (int step = 0; step < NS; ++step) {
        const int cur = step & 1;
        const _Float16* As_ = As[cur];
        const _Float16* Bs_ = Bs[cur];

        const int co0 = ((grp ^ (fr & 7)) << 3);
        h8 af0[MI], bf0[4];
        #pragma unroll
        for (int mi = 0; mi < MI; ++mi)
            af0[mi] = *(const h8*)&As_[(wm + mi * 16 + fr) * 64 + co0];
        #pragma unroll
        for (int ni = 0; ni < 4; ++ni)
            bf0[ni] = *(const h8*)&Bs_[(wn + ni * 16 + fr) * 64 + co0];

        if (step + 1 < NS) stage(step + 1, cur ^ 1);

        #pragma unroll
        for (int mi = 0; mi < MI; ++mi)
            #pragma unroll
            for (int ni = 0; ni < 4; ++ni)
                acc[mi][ni] = __builtin_amdgcn_mfma_f32_16x16x32_f16(
                    af0[mi], bf0[ni], acc[mi][ni], 0, 0, 0);

        const int co1 = (((4 + grp) ^ (fr & 7)) << 3);
        h8 af1[MI], bf1[4];
        #pragma unroll
        for (int mi = 0; mi < MI; ++mi)
            af1[mi] = *(const h8*)&As_[(wm + mi * 16 + fr) * 64 + co1];
        #pragma unroll
        for (int ni = 0; ni < 4; ++ni)
            bf1[ni] = *(const h8*)&Bs_[(wn + ni * 16 + fr) * 64 + co1];
        #pragma unroll
        for (int mi = 0; mi < MI; ++mi)
            #pragma unroll
            for (int ni = 0; ni < 4; ++ni)
                acc[mi][ni] = __builtin_amdgcn_mfma_f32_16x16x32_f16(
                    af1[mi], bf1[ni], acc[mi][ni], 0, 0, 0);

        __syncthreads();
    }

    epilogue<EPI, false, MI>(acc, lane, m0, wm, n0, wn, M, N, 0, bz,
                             Cf, Ch, bias, nullptr, nullptr, nullptr, c_z);
}

// ------------------------- small helper kernels ----------------------------

__global__ void f2h_k(const float* __restrict__ in, _Float16* __restrict__ out,
                      long n, float scale)
{
    long i = (long)blockIdx.x * blockDim.x + threadIdx.x;
    if (i < n) out[i] = (_Float16)(in[i] * scale);
}

// vectorized f32 -> f16, 8 elems/thread (n must be divisible by 8)
__global__ void f2h8_k(const float* __restrict__ in, _Float16* __restrict__ out,
                       long n8)
{
    long i = (long)blockIdx.x * blockDim.x + threadIdx.x;
    if (i >= n8) return;
    f4 a = ((const f4*)in)[2 * i];
    f4 b = ((const f4*)in)[2 * i + 1];
    h8 o;
    #pragma unroll
    for (int j = 0; j < 4; ++j) { o[j] = (_Float16)a[j]; o[4 + j] = (_Float16)b[j]; }
    ((h8*)out)[i] = o;
}

__global__ void f2h_pad_k(const float* __restrict__ in, _Float16* __restrict__ out)
{
    long i = (long)blockIdx.x * blockDim.x + threadIdx.x;
    if (i >= (long)B_ * 398 * FIN) return;
    int  c = (int)(i % FIN);
    long r = i / FIN;
    int  t = (int)(r % 398);
    int  b = (int)(r / 398);
    float v = (t == 0 || t == 397) ? 0.0f
            : in[((long)b * T0 + (t - 1)) * FIN + c];
    out[i] = (_Float16)v;
}

__global__ void zero_pad_k(_Float16* __restrict__ buf, int Tp, int C)
{
    long i = (long)blockIdx.x * blockDim.x + threadIdx.x;
    if (i >= (long)B_ * 2 * C) return;
    int  c = (int)(i % C);
    long r = i / C;
    int  hi = (int)(r % 2);
    int  b  = (int)(r / 2);
    buf[((size_t)b * Tp + (hi ? Tp - 1 : 0)) * C + c] = (_Float16)0.0f;
}

__global__ void pack_qkv_k(const float* __restrict__ wq, const float* __restrict__ wk,
                           const float* __restrict__ wv, _Float16* __restrict__ out)
{
    long i = (long)blockIdx.x * blockDim.x + threadIdx.x;
    if (i >= (long)NL * 2304 * DM) return;
    int  f = (int)(i % DM);
    long r = i / DM;
    int  n = (int)(r % 2304);
    int  l = (int)(r / 2304);
    int  s = n / DM, hn = n % DM, h = hn / DQ, a = hn % DQ;
    const float* src = (s == 0) ? wq : ((s == 1) ? wk : wv);
    out[i] = (_Float16)src[(((long)l * NHEAD + h) * DM + f) * DQ + a];
}

__global__ void pack_wo_k(const float* __restrict__ wo, _Float16* __restrict__ out)
{
    long i = (long)blockIdx.x * blockDim.x + threadIdx.x;
    if (i >= (long)NL * DM * DM) return;
    int  ha = (int)(i % DM);
    long r  = i / DM;
    int  f  = (int)(r % DM);
    int  l  = (int)(r / DM);
    int  h = ha / DQ, a = ha % DQ;
    out[i] = (_Float16)wo[(((long)l * NHEAD + h) * DQ + a) * DM + f];
}

__global__ void pack_conv_k(const float* __restrict__ w, _Float16* __restrict__ out,
                            int Cout, int Cin, int KS)
{
    long i = (long)blockIdx.x * blockDim.x + threadIdx.x;
    if (i >= (long)Cout * Cin * KS) return;
    int  ci = (int)(i % Cin);
    long r  = i / Cin;
    int  co = (int)(r % Cout);
    int  dk = (int)(r / Cout);
    out[i] = (_Float16)w[((long)co * Cin + ci) * KS + dk];
}

__global__ void pack_rel_k(const float* __restrict__ rel, _Float16* __restrict__ out)
{
    long i = (long)blockIdx.x * blockDim.x + threadIdx.x;
    if (i >= (long)NL * NHEAD * POSN * RELK) return;
    int  k = (int)(i & (RELK - 1));
    long r = i >> 7;
    int  n = (int)(r & (POSN - 1));
    long r2 = r >> 8;
    int  h = (int)(r2 & (NHEAD - 1));
    int  l = (int)(r2 >> 3);
    float v = 0.0f;
    if (n < NREL && k < DQ)
        v = rel[(((long)l * NHEAD + h) * NREL + n) * DQ + k] * 0.10206207261596575f;
    out[i] = (_Float16)v;
}

__global__ void concat_k(const float* __restrict__ xlin, const float* __restrict__ cls,
                         float* __restrict__ xf, _Float16* __restrict__ xh)
{
    long i = (long)blockIdx.x * blockDim.x + threadIdx.x;
    if (i >= (long)MSEQ * DM) return;
    int  c = (int)(i % DM);
    long m = i / DM;
    int  b = (int)(m / L_), t = (int)(m % L_);
    float v = (t == 0) ? cls[c] : xlin[((long)b * (L_ - 1) + (t - 1)) * DM + c];
    xf[i] = v;
    xh[i] = (_Float16)v;
}

__global__ __launch_bounds__(256)
void ln_k(const float* x, const float* __restrict__ d,
          const float* __restrict__ g, const float* __restrict__ bb,
          float* xo, _Float16* __restrict__ xh)
{
    long row = blockIdx.x;
    const float* xr = x + row * DM;
    const float* dr = d + row * DM;
    float v[3];
    float s = 0.0f;
    #pragma unroll
    for (int k = 0; k < 3; ++k) {
        int c = threadIdx.x + 256 * k;
        v[k] = xr[c] + dr[c];
        s += v[k];
    }
    __shared__ float red[8];
    #pragma unroll
    for (int o = 32; o; o >>= 1) s += __shfl_xor(s, o, 64);
    int w = threadIdx.x >> 6, lane = threadIdx.x & 63;
    if (lane == 0) red[w] = s;
    __syncthreads();
    s = red[0] + red[1] + red[2] + red[3];
    float mean = s * (1.0f / DM);
    float vs = 0.0f;
    #pragma unroll
    for (int k = 0; k < 3; ++k) { float t = v[k] - mean; vs += t * t; }
    #pragma unroll
    for (int o = 32; o; o >>= 1) vs += __shfl_xor(vs, o, 64);
    if (lane == 0) red[4 + w] = vs;
    __syncthreads();
    vs = red[4] + red[5] + red[6] + red[7];
    float rstd = rsqrtf(vs * (1.0f / DM) + 1e-5f);
    #pragma unroll
    for (int k = 0; k < 3; ++k) {
        int c = threadIdx.x + 256 * k;
        float y = (v[k] - mean) * rstd * g[c] + bb[c];
        xo[row * DM + c] = y;
        xh[row * DM + c] = (_Float16)y;
    }
}

// MFMA fused attention (unchanged — validated rounds 2-14).
constexpr int LP = 128;
constexpr int KP = 104;
constexpr int PP = 136;

__global__ __launch_bounds__(256)
void attn_k(const _Float16* __restrict__ qkv, const _Float16* __restrict__ pos,
            _Float16* __restrict__ o)
{
    __shared__ __align__(16) char smem[60928];
    _Float16* Ks = (_Float16*)smem;
    _Float16* Ps = (_Float16*)smem;
    _Float16* Vt = (_Float16*)(smem + 34816);

    const int h = blockIdx.x, b = blockIdx.y;
    const int tid = threadIdx.x, lane = tid & 63, w = tid >> 6;
    const _Float16* base = qkv + (size_t)b * L_ * 2304 + h * DQ;
    const float qscale = 0.10206207261596575f;

    {
        int row = tid >> 1;
        int c0  = (tid & 1) * 48;
        const bool real = row < L_;
        const _Float16* krow = base + 768 + (size_t)row * 2304;
        #pragma unroll
        for (int q = 0; q < 6; ++q) {
            int c = c0 + q * 8;
            h8 kv;
            #pragma unroll
            for (int e = 0; e < 8; ++e) kv[e] = (_Float16)0.0f;
            if (real) kv = *(const h8*)(krow + c);
            *(h8*)&Ks[row * KP + c] = kv;
        }
        for (int idx = tid; idx < DQ * LP; idx += 256) {
            int a = idx % DQ, j = idx / DQ;
            _Float16 v = (_Float16)0.0f;
            if (j < L_) v = base[1536 + (size_t)j * 2304 + a];
            Vt[a * PP + j] = v;
        }
    }
    __syncthreads();

    const int fr = lane & 15;
    const int fk = (lane >> 4) * 8;
    const int rbase = w * 32 + ((lane >> 4) << 2);

    f4 acc[2][8];
    #pragma unroll
    for (int mi = 0; mi < 2; ++mi)
        #pragma unroll
        for (int ni = 0; ni < 8; ++ni)
            #pragma unroll
            for (int q = 0; q < 4; ++q) acc[mi][ni][q] = 0.0f;

    #pragma unroll
    for (int k0 = 0; k0 < DQ; k0 += 32) {
        h8 a0 = *(const h8*)(base + (size_t)(w * 32 + fr) * 2304 + k0 + fk);
        h8 a1 = *(const h8*)(base + (size_t)(w * 32 + 16 + fr) * 2304 + k0 + fk);
        #pragma unroll
        for (int ni = 0; ni < 8; ++ni) {
            h8 bv = *(const h8*)&Ks[(ni * 16 + fr) * KP + k0 + fk];
            acc[0][ni] = __builtin_amdgcn_mfma_f32_16x16x32_f16(a0, bv, acc[0][ni], 0, 0, 0);
            acc[1][ni] = __builtin_amdgcn_mfma_f32_16x16x32_f16(a1, bv, acc[1][ni], 0, 0, 0);
        }
    }

    const _Float16* posb = pos + ((size_t)h * MSEQ + (size_t)b * L_) * POSN;
    #pragma unroll
    for (int mi = 0; mi < 2; ++mi)
        #pragma unroll
        for (int r = 0; r < 4; ++r) {
            int i = rbase + mi * 16 + r;
            float s[8];
            #pragma unroll
            for (int ni = 0; ni < 8; ++ni) {
                int j = ni * 16 + fr;
                float v = -3.0e38f;
                if (i < L_ && j < L_)
                    v = acc[mi][ni][r] * qscale
                      + (float)posb[(size_t)i * POSN + (j - i + (L_ - 1))];
                s[ni] = v;
            }
            float m = s[0];
            #pragma unroll
            for (int ni = 1; ni < 8; ++ni) m = fmaxf(m, s[ni]);
            #pragma unroll
            for (int msk = 1; msk < 16; msk <<= 1) m = fmaxf(m, __shfl_xor(m, msk, 64));
            float sum = 0.0f;
            #pragma unroll
            for (int ni = 0; ni < 8; ++ni) { s[ni] = __expf(s[ni] - m); sum += s[ni]; }
            #pragma unroll
            for (int msk = 1; msk < 16; msk <<= 1) sum += __shfl_xor(sum, msk, 64);
            float inv = 1.0f / sum;
            #pragma unroll
            for (int ni = 0; ni < 8; ++ni) acc[mi][ni][r] = s[ni] * inv;
        }

    __syncthreads();

    #pragma unroll
    for (int mi = 0; mi < 2; ++mi)
        #pragma unroll
        for (int r = 0; r < 4; ++r) {
            int i = rbase + mi * 16 + r;
            #pragma unroll
            for (int ni = 0; ni < 8; ++ni)
                Ps[i * PP + ni * 16 + fr] = (_Float16)acc[mi][ni][r];
        }
    __syncthreads();

    f4 acc2[2][6];
    #pragma unroll
    for (int mi = 0; mi < 2; ++mi)
        #pragma unroll
        for (int ni = 0; ni < 6; ++ni)
            #pragma unroll
            for (int q = 0; q < 4; ++q) acc2[mi][ni][q] = 0.0f;

    #pragma unroll
    for (int k0 = 0; k0 < LP; k0 += 32) {
        h8 a0 = *(const h8*)&Ps[(w * 32 + fr) * PP + k0 + fk];
        h8 a1 = *(const h8*)&Ps[(w * 32 + 16 + fr) * PP + k0 + fk];
        #pragma unroll
        for (int ni = 0; ni < 6; ++ni) {
            h8 bv = *(const h8*)&Vt[(ni * 16 + fr) * PP + k0 + fk];
            acc2[0][ni] = __builtin_amdgcn_mfma_f32_16x16x32_f16(a0, bv, acc2[0][ni], 0, 0, 0);
            acc2[1][ni] = __builtin_amdgcn_mfma_f32_16x16x32_f16(a1, bv, acc2[1][ni], 0, 0, 0);
        }
    }

    _Float16* ob = o + (size_t)b * L_ * DM + h * DQ;
    #pragma unroll
    for (int mi = 0; mi < 2; ++mi)
        #pragma unroll
        for (int r = 0; r < 4; ++r) {
            int i = rbase + mi * 16 + r;
            if (i < L_) {
                #pragma unroll
                for (int ni = 0; ni < 6; ++ni)
                    ob[(size_t)i * DM + ni * 16 + fr] = (_Float16)acc2[mi][ni][r];
            }
        }
}

__global__ __launch_bounds__(256)
void out_k(const float* __restrict__ xseq, const float* __restrict__ w,
           const float* __restrict__ bias, float* __restrict__ out)
{
    __shared__ float xs[DM];
    int b = blockIdx.x;
    for (int c = threadIdx.x; c < DM; c += 256) xs[c] = xseq[(size_t)b * L_ * DM + c];
    __syncthreads();
    int n = threadIdx.x;
    const f4* wr = (const f4*)(w + (size_t)n * DM);
    float acc = 0.0f;
    #pragma unroll 4
    for (int k4 = 0; k4 < DM / 4; ++k4) {
        f4 wv = wr[k4];
        f4 xv = *(const f4*)&xs[k4 * 4];
        acc += wv[0]*xv[0] + wv[1]*xv[1] + wv[2]*xv[2] + wv[3]*xv[3];
    }
    out[(size_t)b * 256 + n] = acc + bias[n];
}

} // anonymous namespace

// ---------------------------------------------------------------------------
extern "C" void kernel_launch(void* const* d_in, const int* in_sizes, int n_in,
                              void* d_out, int out_size, void* d_ws, size_t ws_size,
                              hipStream_t stream)
{
    (void)in_sizes; (void)n_in; (void)out_size; (void)ws_size;

    const float* x_raw   = (const float*)d_in[0];
    const float* rb1_c1w = (const float*)d_in[1];
    const float* rb1_c1b = (const float*)d_in[2];
    const float* rb1_s1  = (const float*)d_in[3];
    const float* rb1_b1  = (const float*)d_in[4];
    const float* rb1_c2w = (const float*)d_in[5];
    const float* rb1_c2b = (const float*)d_in[6];
    const float* rb1_s2  = (const float*)d_in[7];
    const float* rb1_b2  = (const float*)d_in[8];
    const float* rb1_crw = (const float*)d_in[9];
    const float* rb1_crb = (const float*)d_in[10];
    const float* rb1_sr  = (const float*)d_in[11];
    const float* rb1_br  = (const float*)d_in[12];
    const float* rb2_c1w = (const float*)d_in[13];
    const float* rb2_c1b = (const float*)d_in[14];
    const float* rb2_s1  = (const float*)d_in[15];
    const float* rb2_b1  = (const float*)d_in[16];
    const float* rb2_c2w = (const float*)d_in[17];
    const float* rb2_c2b = (const float*)d_in[18];
    const float* rb2_s2  = (const float*)d_in[19];
    const float* rb2_b2  = (const float*)d_in[20];
    const float* rb2_crw = (const float*)d_in[21];
    const float* rb2_crb = (const float*)d_in[22];
    const float* rb2_sr  = (const float*)d_in[23];
    const float* rb2_br  = (const float*)d_in[24];
    const float* w_in_w  = (const float*)d_in[25];
    const float* w_in_b  = (const float*)d_in[26];
    const float* cls     = (const float*)d_in[27];
    const float* wq      = (const float*)d_in[28];
    const float* wk      = (const float*)d_in[29];
    const float* wv      = (const float*)d_in[30];
    const float* wo      = (const float*)d_in[31];
    const float* rel     = (const float*)d_in[32];
    const float* ln1g    = (const float*)d_in[33];
    const float* ln1b    = (const float*)d_in[34];
    const float* ln2g    = (const float*)d_in[35];
    const float* ln2b    = (const float*)d_in[36];
    const float* ff1w    = (const float*)d_in[37];
    const float* ff1b    = (const float*)d_in[38];
    const float* ff2w    = (const float*)d_in[39];
    const float* ff2b    = (const float*)d_in[40];
    const float* w_out_w = (const float*)d_in[41];
    const float* w_out_b = (const float*)d_in[42];

    char* base = (char*)d_ws;
    size_t off = 0;
    auto carve = [&](size_t bytes) -> char* {
        char* p = base + off;
        off = (off + bytes + 255) & ~(size_t)255;
        return p;
    };
    _Float16* w_in_h = (_Float16*)carve((size_t)589824 * 2);
    _Float16* qkvw   = (_Float16*)carve((size_t)10616832 * 2);
    _Float16* wow    = (_Float16*)carve((size_t)3538944 * 2);
    _Float16* ff1h   = (_Float16*)carve((size_t)14155776 * 2);
    _Float16* ff2h   = (_Float16*)carve((size_t)14155776 * 2);
    _Float16* relh   = (_Float16*)carve((size_t)NL * NHEAD * POSN * RELK * 2);
    _Float16* cw11   = (_Float16*)carve((size_t)294912 * 2);
    _Float16* cw12   = (_Float16*)carve((size_t)1769472 * 2);
    _Float16* cw1r   = (_Float16*)carve((size_t)98304 * 2);
    _Float16* cw21   = (_Float16*)carve((size_t)1769472 * 2);
    _Float16* cw22   = (_Float16*)carve((size_t)1769472 * 2);
    _Float16* cw2r   = (_Float16*)carve((size_t)589824 * 2);
    _Float16* xrawp  = (_Float16*)carve((size_t)B_ * 398 * FIN * 2);
    float*    xseq_f = (float*)carve((size_t)4915200 * 4);
    _Float16* xseq_h = (_Float16*)carve((size_t)4915200 * 2);
    _Float16* qkvb   = (_Float16*)carve((size_t)14745600 * 2);
    _Float16* ohb    = (_Float16*)carve((size_t)4915200 * 2);
    float*    af     = (float*)carve((size_t)4915200 * 4);
    char*     hhreg  = carve((size_t)19660800 * 2);
    float*    yf     = (float*)carve((size_t)4915200 * 4);
    // phase-overlapped aliases (strictly sequential producer->consumer):
    _Float16* h1_rb1 = qkvb;                 // [64][200][768] padded
    _Float16* r_rb1h = (_Float16*)hhreg;     // [12672][768] f16 residual
    _Float16* out1   = (_Float16*)af;        // [64][200][768] padded
    _Float16* h1_rb2 = (_Float16*)xseq_f;    // [64][101][768] padded
    _Float16* r_rb2h = (_Float16*)yf;        // [6336][768] f16 residual
    _Float16* out2   = ohb;                  // [6336][768] plain
    float*    xlin   = (float*)hhreg;
    _Float16* posh   = (_Float16*)hhreg;
    _Float16* ffh    = (_Float16*)hhreg;

    dim3 blk(256, 1, 1);
    auto grd = [](long n) { return dim3((unsigned)((n + 255) / 256), 1, 1); };
    #define NWG(M, N, TM, GZ) dim3((unsigned)(((N) / 128) * (((M) + (TM) - 1) / (TM)) * (GZ)), 1, 1)
    #define GXY(M, N, TM) ((N) / 128), (((N) / 128) * (((M) + (TM) - 1) / (TM)))

    // ---- weight conversion / packing ----
    f2h_pad_k<<<grd((long)B_ * 398 * FIN), blk, 0, stream>>>(x_raw, xrawp);
    zero_pad_k<<<grd((long)B_ * 2 * DM), blk, 0, stream>>>(h1_rb1, 200, DM);
    zero_pad_k<<<grd((long)B_ * 2 * DM), blk, 0, stream>>>(out1, 200, DM);
    zero_pad_k<<<grd((long)B_ * 2 * DM), blk, 0, stream>>>(h1_rb2, 101, DM);
    f2h8_k<<<grd(589824 / 8), blk, 0, stream>>>(w_in_w, w_in_h, 589824 / 8);
    f2h8_k<<<grd(14155776 / 8), blk, 0, stream>>>(ff1w, ff1h, 14155776 / 8);
    f2h8_k<<<grd(14155776 / 8), blk, 0, stream>>>(ff2w, ff2h, 14155776 / 8);
    pack_rel_k<<<grd((long)NL * NHEAD * POSN * RELK), blk, 0, stream>>>(rel, relh);
    pack_qkv_k<<<grd((long)NL * 2304 * DM), blk, 0, stream>>>(wq, wk, wv, qkvw);
    pack_wo_k<<<grd((long)NL * DM * DM), blk, 0, stream>>>(wo, wow);
    pack_conv_k<<<grd(294912), blk, 0, stream>>>(rb1_c1w, cw11, DM, FIN, 3);
    pack_conv_k<<<grd(1769472), blk, 0, stream>>>(rb1_c2w, cw12, DM, DM, 3);
    pack_conv_k<<<grd(98304), blk, 0, stream>>>(rb1_crw, cw1r, DM, FIN, 1);
    pack_conv_k<<<grd(1769472), blk, 0, stream>>>(rb2_c1w, cw21, DM, DM, 3);
    pack_conv_k<<<grd(1769472), blk, 0, stream>>>(rb2_c2w, cw22, DM, DM, 3);
    pack_conv_k<<<grd(589824), blk, 0, stream>>>(rb2_crw, cw2r, DM, DM, 1);

    // ---- resblock 1 (T 396 -> 198); MI=4 ----
    gemm5_k<EPI_CONV_BN_H, false, 4><<<NWG(M1, DM, 128, 1), blk, 0, stream>>>(
        xrawp, cw1r, nullptr, r_rb1h, rb1_crb, rb1_sr, rb1_br, nullptr,
        M1, DM, FIN, FIN, T1, 398, 2, 1, 1, GXY(M1, DM, 128));
    gemm5_k<EPI_CONV_RELU_H, true, 4><<<NWG(M1, DM, 128, 1), blk, 0, stream>>>(
        xrawp, cw11, nullptr, h1_rb1, rb1_c1b, rb1_s1, rb1_b1, nullptr,
        M1, DM, FIN, FIN, T1, 398, 2, 3, 0, GXY(M1, DM, 128));
    gemm5_k<EPI_CONV_ADD_RELU_H, true, 4><<<NWG(M1, DM, 128, 1), blk, 0, stream>>>(
        h1_rb1, cw12, nullptr, out1, rb1_c2b, rb1_s2, rb1_b2, r_rb1h,
        M1, DM, DM, DM, T1, 200, 1, 3, 0, GXY(M1, DM, 128));

    // ---- resblock 2 (T 198 -> 99); MI=2 ----
    gemm5_k<EPI_CONV_BN_H, false, 2><<<NWG(M2, DM, 64, 1), blk, 0, stream>>>(
        out1, cw2r, nullptr, r_rb2h, rb2_crb, rb2_sr, rb2_br, nullptr,
        M2, DM, DM, DM, T2, 200, 2, 1, 1, GXY(M2, DM, 64));
    gemm5_k<EPI_CONV_RELU_H, true, 2><<<NWG(M2, DM, 64, 1), blk, 0, stream>>>(
        out1, cw21, nullptr, h1_rb2, rb2_c1b, rb2_s1, rb2_b1, nullptr,
        M2, DM, DM, DM, T2, 200, 2, 3, 0, GXY(M2, DM, 64));
    gemm5_k<EPI_CONV_ADD_RELU_H, false, 2><<<NWG(M2, DM, 64, 1), blk, 0, stream>>>(
        h1_rb2, cw22, nullptr, out2, rb2_c2b, rb2_s2, rb2_b2, r_rb2h,
        M2, DM, DM, DM, T2, 101, 1, 3, 0, GXY(M2, DM, 64));

    // ---- input projection + cls concat ----
    gemm6_k<EPI_F32, 2><<<NWG(M2, DM, 64, 1), blk, 0, stream>>>(
        out2, w_in_h, xlin, nullptr, w_in_b,
        M2, DM, DM, DM, GXY(M2, DM, 64), 0, 0, 0);
    concat_k<<<grd((long)MSEQ * DM), blk, 0, stream>>>(xlin, cls, xseq_f, xseq_h);

    // ---- transformer layers ----
    for (int l = 0; l < NL; ++l) {
        gemm6_k<EPI_H, 4><<<NWG(MSEQ, 2304, 128, 1), blk, 0, stream>>>(
            xseq_h, qkvw + (size_t)l * 2304 * DM, nullptr, qkvb, nullptr,
            MSEQ, 2304, DM, DM, GXY(MSEQ, 2304, 128), 0, 0, 0);
        gemm6_k<EPI_H, 4><<<NWG(MSEQ, POSN, 128, NHEAD), blk, 0, stream>>>(
            qkvb, relh + (size_t)l * NHEAD * POSN * RELK, nullptr, posh, nullptr,
            MSEQ, POSN, RELK, 2304, GXY(MSEQ, POSN, 128),
            (size_t)DQ, (size_t)POSN * RELK, (size_t)MSEQ * POSN);
        attn_k<<<dim3(NHEAD, B_, 1), blk, 0, stream>>>(qkvb, posh, ohb);
        gemm6_k<EPI_F32, 2><<<NWG(MSEQ, DM, 64, 1), blk, 0, stream>>>(
            ohb, wow + (size_t)l * DM * DM, af, nullptr, nullptr,
            MSEQ, DM, DM, DM, GXY(MSEQ, DM, 64), 0, 0, 0);
        ln_k<<<dim3(MSEQ), blk, 0, stream>>>(xseq_f, af, ln1g + l * DM, ln1b + l * DM,
                                             xseq_f, xseq_h);
        gemm6_k<EPI_RELU_H, 4><<<NWG(MSEQ, DFF, 128, 1), blk, 0, stream>>>(
            xseq_h, ff1h + (size_t)l * DFF * DM, nullptr, ffh, ff1b + l * DFF,
            MSEQ, DFF, DM, DM, GXY(MSEQ, DFF, 128), 0, 0, 0);
        gemm6_k<EPI_F32, 2><<<NWG(MSEQ, DM, 64, 1), blk, 0, stream>>>(
            ffh, ff2h + (size_t)l * DM * DFF, yf, nullptr, ff2b + l * DM,
            MSEQ, DM, DFF, DFF, GXY(MSEQ, DM, 64), 0, 0, 0);
        ln_k<<<dim3(MSEQ), blk, 0, stream>>>(xseq_f, yf, ln2g + l * DM, ln2b + l * DM,
                                             xseq_f, xseq_h);
    }

    out_k<<<dim3(B_), blk, 0, stream>>>(xseq_f, w_out_w, w_out_b, (float*)d_out);
    #undef NWG
    #undef GXY
}